// Round 2
// baseline (1746.834 us; speedup 1.0000x reference)
//
#include <hip/hip_runtime.h>
#include <hip/hip_bf16.h>

// DCell forward, bf16-MFMA. Round-10:
//  * gemm_split reverted to round-8 2-buffer/1-syncthreads body (round-9's
//    3-buf depth-2 + extra barrier REGRESSED: 42.4->45.3 us, FETCH 25->34MB;
//    per-step floors MFMA~780/LDS~900/L2~700 cyc serialize under barrier
//    lockstep at 2.5 blocks/CU -- deeper pipelining is not the lever here).
//  * bn_scaleN launches (x5) eliminated: chunk-partial fold + scale/shift is
//    computed by the LAST-arriving block per column-group inside gemm_small /
//    reduce_bias_stats (store -> threadfence -> sync -> atomic counter ->
//    fence -> fold; device-scope, rocPRIM-lookback-style). 19 -> 14 dispatches.
//    Counters (self-resetting): cntA = bufC+4MiB (zeroed in pack_cvt; s4,s3),
//    cntB = ain0 bytes [0,128) (dead until s1-tanh; zeroed in pack_cvt; s2,s1),
//    cntC = ws+77,725,696 (ain1 tail past s0 partial; zeroed in s1-reduce
//    AFTER s1-gemm's last ain1 read; s0).
//  * pack_x + cvt_w_all remain fused (pack_cvt).
// Swizzle: id = c + 8*(q*nTiles + n), group = q*8+c = (b-tile*T*KS + t*KS + ks).
// Stage cfg (T,I,O,C,Gs): s4(256,16,20,0,16) s3(64,144,20,80,64)
//  s2(16,336,77,80,256) s1(4,1332,308,308,1024) s0(1,5328,1229,1232,4096)

#define BDIM 2048
#define OUTW 341

typedef __attribute__((ext_vector_type(8))) short short8;
typedef __attribute__((ext_vector_type(4))) float float4v;

static __device__ __forceinline__ unsigned short f2bf(float f) {
    union { float f; unsigned u; } c{f};
    unsigned r = c.u + 0x7FFF + ((c.u >> 16) & 1);  // RNE
    return (unsigned short)(r >> 16);
}
static __device__ __forceinline__ float bf2f(unsigned short s) {
    union { unsigned u; float f; } c{(unsigned)s << 16};
    return c.f;
}

static __device__ __forceinline__ float fast_tanh(float x) {
    float ax = __builtin_fabsf(x);
    float e  = __builtin_amdgcn_exp2f(ax * 2.8853900817779268f);  // e^{2|x|}
    float r  = 1.f - 2.f * __builtin_amdgcn_rcpf(e + 1.f);
    return __builtin_copysignf(r, x);
}

// async global->LDS, 16B/lane: wave-uniform base + lane*16.
static __device__ __forceinline__ void stage16(const void* g, void* ldsBase, int lane) {
#if __has_builtin(__builtin_amdgcn_global_load_lds)
    __builtin_amdgcn_global_load_lds(
        (const __attribute__((address_space(1))) unsigned int*)(uintptr_t)g,
        (__attribute__((address_space(3))) unsigned int*)(unsigned int)(uintptr_t)ldsBase,
        16, 0, 0);
#else
    *(uint4*)((char*)ldsBase + lane * 16) = *(const uint4*)g;
#endif
}

// ---- W[t][I][O] fp32 -> WbT[t][Npad][Kpad] bf16 core ----
static __device__ __forceinline__ void cvt_w_body(const float* Wt, unsigned short* dst,
                                                  int I, int O, int Npad, int Kpad,
                                                  int i0, int o0, int tid) {
    __shared__ unsigned short tile[32][33];
    const int c = tid & 31, r0 = tid >> 5;
    #pragma unroll
    for (int rr = 0; rr < 4; rr++) {
        int i = i0 + r0 + rr * 8, o = o0 + c;
        float v = (i < I && o < O) ? Wt[(size_t)i * O + o] : 0.f;
        tile[r0 + rr * 8][c] = f2bf(v);
    }
    __syncthreads();
    #pragma unroll
    for (int rr = 0; rr < 4; rr++) {
        int o = o0 + r0 + rr * 8, k = i0 + c;
        if (o < Npad) dst[(size_t)o * Kpad + k] = tile[c][r0 + rr * 8];
    }
}

// ---- fused: x pack (read once -> bf16 into ain0/ain1 + zero pads) AND
//      W4..W1 -> bf16 WbT conversion. Also zeroes fold counters cntA/cntB.
#define PACK_BLOCKS ((BDIM * 512 + BDIM * 24 + 255) / 256)   // 4288
__global__ __launch_bounds__(256) void pack_cvt(const float* __restrict__ x,
                                                unsigned short* __restrict__ ain0,
                                                unsigned short* __restrict__ ain1,
                                                const float* __restrict__ W4,
                                                const float* __restrict__ W3,
                                                const float* __restrict__ W2,
                                                const float* __restrict__ W1,
                                                unsigned short* __restrict__ wbt,
                                                int* __restrict__ cntA,
                                                int* __restrict__ cntB) {
    int bid = blockIdx.x;
    if (bid == 0) {                           // zero fold counters (1 block, extra stores)
        cntA[threadIdx.x] = 0;                // 256 ints
        if (threadIdx.x < 32) cntB[threadIdx.x] = 0;
    }
    if (bid < PACK_BLOCKS) {
        const int MAIN = BDIM * 512;          // 8-float units
        int i = bid * 256 + threadIdx.x;
        if (i < MAIN) {
            int b = i >> 9, j = i & 511;
            const float* xp = x + (size_t)b * 4096 + j * 8;
            float4 lo = *(const float4*)xp, hi = *(const float4*)(xp + 4);
            union { unsigned short u[8]; uint4 v4; uint2 v2[2]; } t;
            t.u[0] = f2bf(lo.x); t.u[1] = f2bf(lo.y); t.u[2] = f2bf(lo.z); t.u[3] = f2bf(lo.w);
            t.u[4] = f2bf(hi.x); t.u[5] = f2bf(hi.y); t.u[6] = f2bf(hi.z); t.u[7] = f2bf(hi.w);
            *(uint4*)(ain0 + (size_t)b * 5376 + 1232 + j * 8) = t.v4;       // 16B aligned
            int gi = j * 8, tt = gi >> 10, u = gi & 1023;
            unsigned short* d1 = ain1 + (size_t)b * 5376 + tt * 1344 + 308 + u;  // 8B aligned
            *(uint2*)d1 = t.v2[0];
            *(uint2*)(d1 + 4) = t.v2[1];
            return;
        }
        int zi = i - MAIN;                    // zero pads, uint2 (4-short) units
        const int ZU = BDIM * 12;             // per-buffer zero units
        if (zi < ZU) {                        // ain0: cols [5328,5376)
            int b = zi / 12, u = zi % 12;
            *(uint2*)(ain0 + (size_t)b * 5376 + 5328 + u * 4) = make_uint2(0u, 0u);
        } else if (zi < 2 * ZU) {             // ain1: cols [t*1344+1332, +1344)
            zi -= ZU;
            int b = zi / 12, u = zi % 12, tt = u / 3, k = u % 3;
            *(uint2*)(ain1 + (size_t)b * 5376 + tt * 1344 + 1332 + k * 4) = make_uint2(0u, 0u);
        }
        return;
    }
    bid -= PACK_BLOCKS;
    const float* W; unsigned short* dst;
    int I, O, Npad, Kpad, gx, gy, local;
    if (bid < 256)       { W = W4; dst = wbt;           I = 16;   O = 20;  Npad = 20;  Kpad = 32;   gx = 1;  gy = 1;  local = bid; }
    else if (bid < 640)  { W = W3; dst = wbt + 163840;  I = 144;  O = 20;  Npad = 20;  Kpad = 192;  gx = 6;  gy = 1;  local = bid - 256; }
    else if (bid < 1216) { W = W2; dst = wbt + 409600;  I = 336;  O = 77;  Npad = 77;  Kpad = 384;  gx = 12; gy = 3;  local = bid - 640; }
    else                 { W = W1; dst = wbt + 882688;  I = 1332; O = 308; Npad = 320; Kpad = 1344; gx = 42; gy = 10; local = bid - 1216; }
    int per = gx * gy;
    int t = local / per, rem = local % per;
    int by = rem / gx, bx = rem % gx;
    cvt_w_body(W + (size_t)t * I * O, dst + (size_t)t * Npad * Kpad,
               I, O, Npad, Kpad, bx * 32, by * 32, threadIdx.x);
}

__global__ __launch_bounds__(256) void cvt_w(const float* __restrict__ W,
                                             unsigned short* __restrict__ WbT,
                                             int I, int O, int Npad, int Kpad) {
    cvt_w_body(W + (size_t)blockIdx.z * I * O, WbT + (size_t)blockIdx.z * Npad * Kpad,
               I, O, Npad, Kpad, blockIdx.x * 32, blockIdx.y * 32, threadIdx.x);
}

// ---- small-stage GEMM + fused column stats + last-block scale/shift fold ----
// chunk = blockIdx.y (gridDim.y chunks of 64 rows). Last-arriving block per
// column-group (t, blockIdx.x) folds sp -> ss (replaces bn_scaleN launch).
template <int BN, int BK>
__global__ __launch_bounds__(256) void gemm_small(
    const unsigned short* __restrict__ actb,  // [B][T*C] bf16 (null if C==0)
    const unsigned short* __restrict__ xg,    // bf16 x copy, row stride 5376
    const unsigned short* __restrict__ WbT,   // [T][O][Kpad] bf16
    const float* __restrict__ bias,
    unsigned short* __restrict__ h,           // [B][hstride]
    float* __restrict__ sp,                   // [NC][2*TO] col-sum partials
    float* __restrict__ ssOut,                // [2*TO] scale/shift
    const float* __restrict__ g,
    const float* __restrict__ bb,
    int* __restrict__ cnt,                    // per-(t,bx) arrival counters
    int T, int I, int O, int C, int Gs, int Kpad, int hstride, int TO)
{
    const int t  = blockIdx.z;
    const int b0 = blockIdx.y * 64;
    const int o0 = blockIdx.x * BN;
    const int tid = threadIdx.x;
    const int lane = tid & 63;
    const int w = tid >> 6;
    const int l15 = lane & 15;
    const int quad = lane >> 4;

    constexpr int NF = BN / 32;
    const int wm = (w & 1) * 32;
    const int wn = (w >> 1) * (BN / 2);

    __shared__ __align__(16) unsigned short As[64][BK + 8];
    __shared__ __align__(16) unsigned short Bs[BN][BK + 8];
    __shared__ float ldsS[2][BN], ldsS2[2][BN];

    float4v acc[2][NF];
    #pragma unroll
    for (int a = 0; a < 2; a++)
        #pragma unroll
        for (int b = 0; b < NF; b++)
            acc[a][b] = (float4v){0.f, 0.f, 0.f, 0.f};

    constexpr int GR = BK / 8;
    constexpr int AG = 64 * GR;
    constexpr int BG = BN * GR;
    const size_t actRow = (size_t)T * C;

    for (int k0 = 0; k0 < Kpad; k0 += BK) {
        #pragma unroll
        for (int gg = tid; gg < AG; gg += 256) {
            const int r = gg / GR, c8 = gg % GR;
            const int k = k0 + c8 * 8;
            const int b = b0 + r;
            uint4 v;
            if (k + 8 <= C) {
                v = *(const uint4*)(actb + (size_t)b * actRow + (size_t)t * C + k);
            } else if (k >= I) {
                v = make_uint4(0u, 0u, 0u, 0u);
            } else {
                v = *(const uint4*)(xg + (size_t)b * 5376 + (size_t)t * Gs + (k - C));
            }
            *(uint4*)&As[r][c8 * 8] = v;
        }
        #pragma unroll
        for (int gg = tid; gg < BG; gg += 256) {
            const int n = gg / GR, c8 = gg % GR;
            const int o = o0 + n;
            uint4 v = make_uint4(0u, 0u, 0u, 0u);
            if (o < O)
                v = *(const uint4*)(WbT + ((size_t)t * O + o) * Kpad + k0 + c8 * 8);
            *(uint4*)&Bs[n][c8 * 8] = v;
        }
        __syncthreads();
        #pragma unroll
        for (int ks = 0; ks < BK / 32; ks++) {
            const int koff = ks * 32 + quad * 8;
            short8 a0 = *(const short8*)&As[wm + l15][koff];
            short8 a1 = *(const short8*)&As[wm + 16 + l15][koff];
            #pragma unroll
            for (int fn = 0; fn < NF; fn++) {
                short8 bf = *(const short8*)&Bs[wn + fn * 16 + l15][koff];
                acc[0][fn] = __builtin_amdgcn_mfma_f32_16x16x32_bf16(a0, bf, acc[0][fn], 0, 0, 0);
                acc[1][fn] = __builtin_amdgcn_mfma_f32_16x16x32_bf16(a1, bf, acc[1][fn], 0, 0, 0);
            }
        }
        __syncthreads();
    }

    // epilogue + per-thread column partial sums (fp32, pre-rounding)
    float csum[NF], csum2[NF];
    #pragma unroll
    for (int fn = 0; fn < NF; fn++) { csum[fn] = 0.f; csum2[fn] = 0.f; }
    #pragma unroll
    for (int fm = 0; fm < 2; fm++)
        #pragma unroll
        for (int fn = 0; fn < NF; fn++)
            #pragma unroll
            for (int r = 0; r < 4; r++) {
                int m = wm + fm * 16 + quad * 4 + r;
                int o = o0 + wn + fn * 16 + l15;
                if (o < O) {
                    float v = acc[fm][fn][r] + bias[t * O + o];
                    h[(size_t)(b0 + m) * hstride + (size_t)t * O + o] = f2bf(v);
                    csum[fn] += v; csum2[fn] += v * v;
                }
            }
    #pragma unroll
    for (int fn = 0; fn < NF; fn++) {
        csum[fn]  += __shfl_xor(csum[fn], 16, 64);
        csum[fn]  += __shfl_xor(csum[fn], 32, 64);
        csum2[fn] += __shfl_xor(csum2[fn], 16, 64);
        csum2[fn] += __shfl_xor(csum2[fn], 32, 64);
    }
    if (quad == 0) {
        #pragma unroll
        for (int fn = 0; fn < NF; fn++) {
            ldsS[w & 1][wn + fn * 16 + l15]  = csum[fn];
            ldsS2[w & 1][wn + fn * 16 + l15] = csum2[fn];
        }
    }
    __syncthreads();
    if (tid < BN && o0 + tid < O) {
        int col = t * O + o0 + tid;
        size_t base = (size_t)blockIdx.y * 2 * TO;
        sp[base + col]      = ldsS[0][tid] + ldsS[1][tid];
        sp[base + TO + col] = ldsS2[0][tid] + ldsS2[1][tid];
    }

    // ---- last-arriving block of this column-group folds sp -> ss ----
    __threadfence();
    __syncthreads();
    __shared__ int lastFlag;
    if (tid == 0)
        lastFlag = (atomicAdd(&cnt[t * gridDim.x + blockIdx.x], 1) == (int)gridDim.y - 1) ? 1 : 0;
    __syncthreads();
    if (lastFlag) {
        __threadfence();   // acquire side
        if (tid < BN && o0 + tid < O) {
            int col = t * O + o0 + tid;
            float s = 0.f, s2 = 0.f;
            for (int ch = 0; ch < (int)gridDim.y; ch++) {
                s  += sp[(size_t)ch * 2 * TO + col];
                s2 += sp[(size_t)ch * 2 * TO + TO + col];
            }
            float mu = s * (1.f / BDIM);
            float var = s2 * (1.f / BDIM) - mu * mu;  // biased, matches jnp.var
            float scale = rsqrtf(var + 1e-5f) * g[col];
            ssOut[col] = scale;
            ssOut[TO + col] = bb[col] - mu * scale;
        }
        if (tid == 0) cnt[t * gridDim.x + blockIdx.x] = 0;   // self-reset for reuse
    }
}

// ---- big-stage GEMM (s1/s0): 128-row tile, BK=32, dbuf LDS, XCD-swizzled 1D grid
// (round-8 proven body). id = c + 8*(q*nTiles + n); group = q*8+c =
// b*TKS + t*KS + ks. Same-A blocks (all n, fixed group) share XCD c.
// LDS slot = row*4+pos, pos = kg ^ ((row>>1)&3).
template <int BN>
__global__ __launch_bounds__(256) void gemm_split(
    const unsigned short* __restrict__ A,     // [2048][aStride] bf16 (zero-padded)
    const unsigned short* __restrict__ WbT,   // [T][Npad][Kpad] bf16 (zero-padded)
    float* __restrict__ partial,              // [KS][2048][TNpad]
    int aStride, int tStride, int Kpad, int Npad, int KS, int TNpad,
    int nTiles, int TKS)
{
    const int tid = threadIdx.x;
    const int lane = tid & 63, w = tid >> 6;
    const int l15 = lane & 15, quad = lane >> 4;

    // swizzled decode
    const int id = blockIdx.x;
    const int c = id & 7;
    const int tmp = id >> 3;
    const int n = tmp % nTiles;
    const int q = tmp / nTiles;
    const int group = q * 8 + c;
    const int b0 = (group / TKS) * 128;
    const int rem = group % TKS;
    const int t = rem / KS;
    const int ksIdx = rem - t * KS;
    const int n0 = n * BN;

    __shared__ __align__(16) unsigned short As[2][128 * 32];   // 2 x 8 KB
    __shared__ __align__(16) unsigned short Bs[2][BN * 32];    // 2 x 8/4 KB

    const int S = Kpad >> 5;
    const int qb = S / KS, rb = S % KS;
    const int beg = ksIdx * qb + (ksIdx < rb ? ksIdx : rb);
    const int cnt = qb + (ksIdx < rb ? 1 : 0);

    constexpr int NF = BN / 32;
    const int wm = (w & 1) * 64;
    const int wn = (w >> 1) * (BN / 2);

    float4v acc[4][NF];
    #pragma unroll
    for (int a = 0; a < 4; a++)
        #pragma unroll
        for (int b = 0; b < NF; b++)
            acc[a][b] = (float4v){0.f, 0.f, 0.f, 0.f};

    // A staging: 512 granule-slots, 2 calls/wave
    const unsigned short* aSrc[2];
    int aOff[2];
    #pragma unroll
    for (int j = 0; j < 2; j++) {
        int s = (w * 2 + j) * 64 + lane;
        int r = s >> 2, kg = (s & 3) ^ ((r >> 1) & 3);
        aSrc[j] = A + (size_t)(b0 + r) * aStride + (size_t)t * tStride + kg * 8;
        aOff[j] = (w * 2 + j) * 512;           // shorts
    }
    // B staging
    constexpr int BCALLS = (BN == 128) ? 2 : 1;
    const unsigned short* bSrc[BCALLS];
    int bOff[BCALLS];
    #pragma unroll
    for (int j = 0; j < BCALLS; j++) {
        int s = (w * BCALLS + j) * 64 + lane;
        int r = s >> 2, kg = (s & 3) ^ ((r >> 1) & 3);
        bSrc[j] = WbT + ((size_t)t * Npad + n0 + r) * Kpad + kg * 8;
        bOff[j] = (w * BCALLS + j) * 512;
    }

    // prologue: stage step 0 into buf 0
    {
        const int k0 = beg << 5;
        #pragma unroll
        for (int j = 0; j < 2; j++)      stage16(aSrc[j] + k0, &As[0][aOff[j]], lane);
        #pragma unroll
        for (int j = 0; j < BCALLS; j++) stage16(bSrc[j] + k0, &Bs[0][bOff[j]], lane);
    }

    for (int s = 0; s < cnt; s++) {
        const int cur = s & 1;
        __syncthreads();   // drains cur-buf loads (in flight since prev iter) + prev compute
        if (s + 1 < cnt) {
            const int k1 = (beg + s + 1) << 5;
            #pragma unroll
            for (int j = 0; j < 2; j++)      stage16(aSrc[j] + k1, &As[cur ^ 1][aOff[j]], lane);
            #pragma unroll
            for (int j = 0; j < BCALLS; j++) stage16(bSrc[j] + k1, &Bs[cur ^ 1][bOff[j]], lane);
        }
        short8 af[4];
        #pragma unroll
        for (int fm = 0; fm < 4; fm++) {
            int m = wm + fm * 16 + l15;
            int pos = quad ^ ((m >> 1) & 3);
            af[fm] = *(const short8*)&As[cur][(m * 4 + pos) * 8];
        }
        short8 bfr[NF];
        #pragma unroll
        for (int fn = 0; fn < NF; fn++) {
            int nn = wn + fn * 16 + l15;
            int pos = quad ^ ((nn >> 1) & 3);
            bfr[fn] = *(const short8*)&Bs[cur][(nn * 4 + pos) * 8];
        }
        #pragma unroll
        for (int fm = 0; fm < 4; fm++)
            #pragma unroll
            for (int fn = 0; fn < NF; fn++)
                acc[fm][fn] = __builtin_amdgcn_mfma_f32_16x16x32_bf16(af[fm], bfr[fn], acc[fm][fn], 0, 0, 0);
    }

    const size_t pBase = ((size_t)ksIdx * BDIM + b0) * TNpad + (size_t)t * Npad + n0;
    #pragma unroll
    for (int fm = 0; fm < 4; fm++)
        #pragma unroll
        for (int r = 0; r < 4; r++) {
            const int m = wm + fm * 16 + quad * 4 + r;
            float* prow = partial + pBase + (size_t)m * TNpad + wn;
            #pragma unroll
            for (int fn = 0; fn < NF; fn++)
                prow[fn * 16 + l15] = acc[fm][fn][r];
        }
}

// ---- fused split-K reduce + bias + bf16 h store + stats partials +
//      last-block scale/shift fold (replaces bn_scaleN). Optionally zeroes
//      the NEXT stage's counters (zc) -- safe here: runs after s1-gemm's
//      last read of ain1.
__global__ __launch_bounds__(256) void reduce_bias_stats(
    const float* __restrict__ partial, const float* __restrict__ bias,
    unsigned short* __restrict__ h, float* __restrict__ sp,
    float* __restrict__ ssOut, const float* __restrict__ g,
    const float* __restrict__ bb, int* __restrict__ cnt,
    int* __restrict__ zc,
    int T, int O, int Npad, int KS, int hstride, int TO)
{
    if (zc && blockIdx.x == 0 && blockIdx.y == 0 && threadIdx.x < 32)
        zc[threadIdx.x] = 0;
    __shared__ float redS[4][64], redS2[4][64];
    const int colL = threadIdx.x & 63;
    const int cr = threadIdx.x >> 6;
    const int col = blockIdx.x * 64 + colL;
    const int chunk = blockIdx.y;
    float s = 0.f, s2 = 0.f;
    if (col < TO) {
        int t = col / O, o = col - t * O;
        const size_t TNpad = (size_t)T * Npad;
        const size_t pcol = (size_t)t * Npad + o;
        const float bv = bias[col];
        const int row0 = chunk * 128 + cr * 32;
        for (int r = 0; r < 32; r++) {
            const int row = row0 + r;
            const float* p = partial + (size_t)row * TNpad + pcol;
            float v = bv;
            for (int ks = 0; ks < KS; ks++) v += p[(size_t)ks * BDIM * TNpad];
            h[(size_t)row * hstride + col] = f2bf(v);
            s += v; s2 += v * v;
        }
    }
    redS[cr][colL] = s; redS2[cr][colL] = s2;
    __syncthreads();
    if (cr == 0 && col < TO) {
        float ts  = redS[0][colL] + redS[1][colL] + redS[2][colL] + redS[3][colL];
        float ts2 = redS2[0][colL] + redS2[1][colL] + redS2[2][colL] + redS2[3][colL];
        sp[(size_t)chunk * 2 * TO + col] = ts;
        sp[(size_t)chunk * 2 * TO + TO + col] = ts2;
    }

    // ---- last-arriving block of this column-group folds sp -> ss ----
    __threadfence();
    __syncthreads();
    __shared__ int lastFlag;
    if (threadIdx.x == 0)
        lastFlag = (atomicAdd(&cnt[blockIdx.x], 1) == (int)gridDim.y - 1) ? 1 : 0;
    __syncthreads();
    if (lastFlag) {
        __threadfence();   // acquire side
        if (threadIdx.x < 64) {
            int fcol = blockIdx.x * 64 + threadIdx.x;
            if (fcol < TO) {
                float fs = 0.f, fs2 = 0.f;
                for (int ch = 0; ch < (int)gridDim.y; ch++) {
                    fs  += sp[(size_t)ch * 2 * TO + fcol];
                    fs2 += sp[(size_t)ch * 2 * TO + TO + fcol];
                }
                float mu = fs * (1.f / BDIM);
                float var = fs2 * (1.f / BDIM) - mu * mu;  // biased, matches jnp.var
                float scale = rsqrtf(var + 1e-5f) * g[fcol];
                ssOut[fcol] = scale;
                ssOut[TO + fcol] = bb[fcol] - mu * scale;
            }
        }
        if (threadIdx.x == 0) cnt[blockIdx.x] = 0;   // self-reset for reuse
    }
}

// ---- vectorized BN+tanh+head for O=20 in-place stages (s4/s3) ----
template <int GPT>
__global__ __launch_bounds__(256) void bn_tanh_head_vec(
    unsigned short* hact, const float* __restrict__ ss,
    const float* __restrict__ hw, const float* __restrict__ hb,
    float* __restrict__ out,
    int T, int rowGran, int RPB, int hstride, int head_off)
{
    __shared__ float headAcc[256];
    const int tid = threadIdx.x;
    headAcc[tid] = 0.f;
    __syncthreads();
    const int b0 = blockIdx.x * RPB;

    uint2 hv[GPT];
    #pragma unroll
    for (int j = 0; j < GPT; j++) {
        int G = tid + j * 256;
        int r = G / rowGran, gg = G % rowGran;
        hv[j] = *(const uint2*)(hact + (size_t)(b0 + r) * hstride + gg * 4);
    }
    #pragma unroll
    for (int j = 0; j < GPT; j++) {
        int G = tid + j * 256;
        int r = G / rowGran, gg = G % rowGran;
        int c = gg * 4;
        float4 sc = *(const float4*)(ss + c);
        float4 sh = *(const float4*)(ss + hstride + c);
        float4 w4 = *(const float4*)(hw + c);
        union { unsigned short u[4]; uint2 v; } iv, ov;
        iv.v = hv[j];
        float a0 = fast_tanh(bf2f(iv.u[0]) * sc.x + sh.x);
        float a1 = fast_tanh(bf2f(iv.u[1]) * sc.y + sh.y);
        float a2 = fast_tanh(bf2f(iv.u[2]) * sc.z + sh.z);
        float a3 = fast_tanh(bf2f(iv.u[3]) * sc.w + sh.w);
        ov.u[0] = f2bf(a0); ov.u[1] = f2bf(a1); ov.u[2] = f2bf(a2); ov.u[3] = f2bf(a3);
        *(uint2*)(hact + (size_t)(b0 + r) * hstride + c) = ov.v;
        float partial = a0 * w4.x + a1 * w4.y + a2 * w4.z + a3 * w4.w;
        int t = gg / 5;
        atomicAdd(&headAcc[r * T + t], partial);
    }
    __syncthreads();
    if (tid < RPB * T) {
        int r = tid / T, t = tid % T;
        out[(size_t)(b0 + r) * OUTW + head_off + t] = headAcc[tid] + hb[t];
    }
}

// ---- BN + tanh + strided act store + head — WAVE variant ----
__global__ __launch_bounds__(256) void bn_tanh_head(
    const unsigned short* __restrict__ h, const float* __restrict__ ss,
    const float* __restrict__ hw, const float* __restrict__ hb,
    unsigned short* __restrict__ actOut, float* __restrict__ out,
    int T, int O, int hstride, int aRow, int GT, int GS, int head_off, int TO)
{
    int wid  = (blockIdx.x * 256 + threadIdx.x) >> 6;
    int lane = threadIdx.x & 63;
    int b = wid / T;
    int t = wid % T;
    const size_t hbase = (size_t)b * hstride + (size_t)t * O;
    const size_t abase = (size_t)b * aRow + (size_t)(t / GT) * GS + (size_t)(t % GT) * O;
    float hsum = 0.f;
    for (int o = lane; o < O; o += 64) {
        int col = t * O + o;
        float a = fast_tanh(bf2f(h[hbase + o]) * ss[col] + ss[TO + col]);
        if (actOut) actOut[abase + o] = f2bf(a);
        hsum += a * hw[col];
    }
    #pragma unroll
    for (int off = 32; off > 0; off >>= 1) hsum += __shfl_down(hsum, off, 64);
    if (lane == 0) out[(size_t)b * OUTW + head_off + t] = hsum + hb[t];
}

extern "C" void kernel_launch(void* const* d_in, const int* in_sizes, int n_in,
                              void* d_out, int out_size, void* d_ws, size_t ws_size,
                              hipStream_t stream)
{
    const float* x = (const float*)d_in[0];
    float* out = (float*)d_out;
    char* ws = (char*)d_ws;

    // ws layout (bytes)
    unsigned short* wbt  = (unsigned short*)(ws);              // 13,762,560
    unsigned short* ain0 = (unsigned short*)(ws + 13762560);   // 22,020,096 (2048x5376)
    unsigned short* bufA = (unsigned short*)(ws + 35782656);   // 20,971,520
    unsigned short* bufB = (unsigned short*)(ws + 56754176);   //  5,242,880
    unsigned short* ain1 = (unsigned short*)(ws + 61997056);   // 22,020,096
    unsigned short* bufC = (unsigned short*)(ws + 84017152);   //  5,046,272
    float*          ss   = (float*)(ws + 89063424);            //     40,960
    float*          sp0  = (float*)(ws + 89104384);            //    157,312 (16x2x1229)
    // overlays (all verified dead at use time):
    float* partial = (float*)(ws + 35782656);   // s1: 21 MB (=bufA), s0: 41.9 MB (bufA..ain1 head)
    float* sp4 = (float*)bufC;                  // 32x2x5120x4 = 1.31 MB (bufC free pre-s2)
    float* sp3 = (float*)bufC;                  // 0.33 MB
    float* sp2 = (float*)bufA;                  // 0.32 MB (act4 dead after s3 gemm)
    float* sp1 = (float*)bufB;                  // 0.32 MB (act3 dead after s2 gemm)
    unsigned short* xg = ain0 + 1232;           // full bf16 x copy, row stride 5376
    // fold counters (all in verified-dead windows, self-resetting):
    int* cntA = (int*)(ws + 88211456);  // bufC+4MiB: s4 (256), then s3 (64); zeroed by pack_cvt
    int* cntB = (int*)(ws + 13762560);  // ain0 row0 cols0..63: s2 (32), then s1 (20); zeroed by pack_cvt
    int* cntC = (int*)(ws + 77725696);  // ain1 tail just past s0 partial: s0 (20); zeroed in s1-reduce

    const float* W4 = (const float*)d_in[1];  const float* b4 = (const float*)d_in[2];
    const float* g4 = (const float*)d_in[3];  const float* bb4 = (const float*)d_in[4];
    const float* hw4 = (const float*)d_in[5]; const float* hb4 = (const float*)d_in[6];
    const float* W3 = (const float*)d_in[7];  const float* b3 = (const float*)d_in[8];
    const float* g3 = (const float*)d_in[9];  const float* bb3 = (const float*)d_in[10];
    const float* hw3 = (const float*)d_in[11]; const float* hb3 = (const float*)d_in[12];
    const float* W2 = (const float*)d_in[13]; const float* b2 = (const float*)d_in[14];
    const float* g2 = (const float*)d_in[15]; const float* bb2 = (const float*)d_in[16];
    const float* hw2 = (const float*)d_in[17]; const float* hb2 = (const float*)d_in[18];
    const float* W1 = (const float*)d_in[19]; const float* b1 = (const float*)d_in[20];
    const float* g1 = (const float*)d_in[21]; const float* bb1 = (const float*)d_in[22];
    const float* hw1 = (const float*)d_in[23]; const float* hb1 = (const float*)d_in[24];
    const float* W0 = (const float*)d_in[25]; const float* b0_ = (const float*)d_in[26];
    const float* g0 = (const float*)d_in[27]; const float* bb0 = (const float*)d_in[28];
    const float* hw0 = (const float*)d_in[29]; const float* hb0 = (const float*)d_in[30];

    // 1: fused x pack + weight conversions (s4..s1) + counter zeroing
    pack_cvt<<<PACK_BLOCKS + 2896, 256, 0, stream>>>(x, ain0, ain1, W4, W3, W2, W1, wbt,
                                                     cntA, cntB);

    // s4: T=256 I=16 O=20 Kpad=32, WbT @0  (fold -> ss fused)
    gemm_small<32, 32><<<dim3(1, 32, 256), 256, 0, stream>>>(nullptr, xg, wbt, b4, bufA,
                                                             sp4, ss, g4, bb4, cntA,
                                                             256, 16, 20, 0, 16, 32, 5120, 5120);
    bn_tanh_head_vec<5><<<BDIM, 256, 0, stream>>>(bufA, ss, hw4, hb4, out, 256, 1280, 1, 5120, 0);

    // s3: T=64 I=144 O=20 Kpad=192, WbT @163840
    gemm_small<32, 64><<<dim3(1, 32, 64), 256, 0, stream>>>(bufA, xg, wbt + 163840, b3, bufB,
                                                            sp3, ss, g3, bb3, cntA,
                                                            64, 144, 20, 80, 64, 192, 1280, 1280);
    bn_tanh_head_vec<5><<<BDIM / 4, 256, 0, stream>>>(bufB, ss, hw3, hb3, out, 64, 320, 4, 1280, 256);

    // s2: T=16 I=336 O=77 Kpad=384, WbT @409600
    gemm_small<64, 64><<<dim3(2, 32, 16), 256, 0, stream>>>(bufB, xg, wbt + 409600, b2, bufC,
                                                            sp2, ss, g2, bb2, cntB,
                                                            16, 336, 77, 80, 256, 384, 1232, 1232);
    bn_tanh_head<<<BDIM * 16 / 4, 256, 0, stream>>>(bufC, ss, hw2, hb2,
                                                    ain1, out, 16, 77, 1232, 5376, 4, 1344, 320, 1232);

    // s1: T=4 I=1332 O=308 Kpad=1344 Npad=320 KS=2, WbT @882688
    // swizzled 1D grid: nTiles=5, TKS=T*KS=8, blocks = 5*16*8 = 640
    gemm_split<64><<<640, 256, 0, stream>>>(ain1, wbt + 882688, partial,
                                            5376, 1344, 1344, 320, 2, 1280, 5, 8);
    cvt_w<<<dim3(168, 40, 1), 256, 0, stream>>>(W0, wbt, 5328, 1229, 1280, 5376);
    reduce_bias_stats<<<dim3(20, 16), 256, 0, stream>>>(partial, b1, bufC, sp1,
                                                        ss, g1, bb1, cntB, cntC,
                                                        4, 308, 320, 2, 1232, 1232);
    bn_tanh_head<<<BDIM * 4 / 4, 256, 0, stream>>>(bufC, ss, hw1, hb1,
                                                   ain0, out, 4, 308, 1232, 5376, 4, 0, 336, 1232);

    // s0: T=1 I=5328 O=1229 Kpad=5376 Npad=1280 KS=4
    // swizzled 1D grid: nTiles=10, TKS=4, blocks = 10*16*4 = 640
    gemm_split<128><<<640, 256, 0, stream>>>(ain0, wbt, partial,
                                             5376, 0, 5376, 1280, 4, 1280, 10, 4);
    reduce_bias_stats<<<dim3(20, 16), 256, 0, stream>>>(partial, b0_, bufC, sp0,
                                                        ss, g0, bb0, cntC, nullptr,
                                                        1, 1229, 1280, 4, 1232, 1229);
    bn_tanh_head<<<BDIM / 4, 256, 0, stream>>>(bufC, ss, hw0, hb0,
                                               nullptr, out, 1, 1229, 1232, 1232, 1, 0, 340, 1229);
}

// Round 3
// 495.348 us; speedup vs baseline: 3.5265x; 3.5265x over previous
//
#include <hip/hip_runtime.h>
#include <hip/hip_bf16.h>

// DCell forward, bf16-MFMA. Round-11:
//  * FULL REVERT of round-10's last-block fold (__threadfence = buffer_wbl2
//    L2-writeback per block on gfx950 -> 4x total regression). bn_scaleN is
//    back as 5 tiny launches; gemm_small/reduce_bias_stats are round-8 bodies.
//  * gemm_split: B operand now DIRECT global->register, double-buffered one
//    K-step ahead (removes B LDS write 8KB/step + B LDS read 16KB/step;
//    per-step LDS traffic 48KB -> 24KB). Theory: step time ~970cyc matches
//    the 48KB/step LDS-pipe floor (MfmaUtil 25%, 0 bank conflicts, HBM 20%)
//    -> kernel is LDS-BW-bound. B tile is 0.34MB, L2-resident; prefetch gets
//    a full compute phase of cover (syncthreads drains vmcnt). A unchanged:
//    global_load_lds + swizzled LDS (A is the cross-n-tile shared operand).
//  * pack_x + cvt_w_all remain fused (pack_cvt).
// Swizzle: id = c + 8*(q*nTiles + n), group = q*8+c = (b-tile*T*KS + t*KS + ks).
// Stage cfg (T,I,O,C,Gs): s4(256,16,20,0,16) s3(64,144,20,80,64)
//  s2(16,336,77,80,256) s1(4,1332,308,308,1024) s0(1,5328,1229,1232,4096)

#define BDIM 2048
#define OUTW 341

typedef __attribute__((ext_vector_type(8))) short short8;
typedef __attribute__((ext_vector_type(4))) float float4v;

static __device__ __forceinline__ unsigned short f2bf(float f) {
    union { float f; unsigned u; } c{f};
    unsigned r = c.u + 0x7FFF + ((c.u >> 16) & 1);  // RNE
    return (unsigned short)(r >> 16);
}
static __device__ __forceinline__ float bf2f(unsigned short s) {
    union { unsigned u; float f; } c{(unsigned)s << 16};
    return c.f;
}

static __device__ __forceinline__ float fast_tanh(float x) {
    float ax = __builtin_fabsf(x);
    float e  = __builtin_amdgcn_exp2f(ax * 2.8853900817779268f);  // e^{2|x|}
    float r  = 1.f - 2.f * __builtin_amdgcn_rcpf(e + 1.f);
    return __builtin_copysignf(r, x);
}

// async global->LDS, 16B/lane: wave-uniform base + lane*16.
static __device__ __forceinline__ void stage16(const void* g, void* ldsBase, int lane) {
#if __has_builtin(__builtin_amdgcn_global_load_lds)
    __builtin_amdgcn_global_load_lds(
        (const __attribute__((address_space(1))) unsigned int*)(uintptr_t)g,
        (__attribute__((address_space(3))) unsigned int*)(unsigned int)(uintptr_t)ldsBase,
        16, 0, 0);
#else
    *(uint4*)((char*)ldsBase + lane * 16) = *(const uint4*)g;
#endif
}

// ---- W[t][I][O] fp32 -> WbT[t][Npad][Kpad] bf16 core ----
static __device__ __forceinline__ void cvt_w_body(const float* Wt, unsigned short* dst,
                                                  int I, int O, int Npad, int Kpad,
                                                  int i0, int o0, int tid) {
    __shared__ unsigned short tile[32][33];
    const int c = tid & 31, r0 = tid >> 5;
    #pragma unroll
    for (int rr = 0; rr < 4; rr++) {
        int i = i0 + r0 + rr * 8, o = o0 + c;
        float v = (i < I && o < O) ? Wt[(size_t)i * O + o] : 0.f;
        tile[r0 + rr * 8][c] = f2bf(v);
    }
    __syncthreads();
    #pragma unroll
    for (int rr = 0; rr < 4; rr++) {
        int o = o0 + r0 + rr * 8, k = i0 + c;
        if (o < Npad) dst[(size_t)o * Kpad + k] = tile[c][r0 + rr * 8];
    }
}

// ---- fused: x pack (read once -> bf16 into ain0/ain1 + zero pads) AND
//      W4..W1 -> bf16 WbT conversion. Disjoint inputs/outputs, no ordering.
#define PACK_BLOCKS ((BDIM * 512 + BDIM * 24 + 255) / 256)   // 4288
__global__ __launch_bounds__(256) void pack_cvt(const float* __restrict__ x,
                                                unsigned short* __restrict__ ain0,
                                                unsigned short* __restrict__ ain1,
                                                const float* __restrict__ W4,
                                                const float* __restrict__ W3,
                                                const float* __restrict__ W2,
                                                const float* __restrict__ W1,
                                                unsigned short* __restrict__ wbt) {
    int bid = blockIdx.x;
    if (bid < PACK_BLOCKS) {
        const int MAIN = BDIM * 512;          // 8-float units
        int i = bid * 256 + threadIdx.x;
        if (i < MAIN) {
            int b = i >> 9, j = i & 511;
            const float* xp = x + (size_t)b * 4096 + j * 8;
            float4 lo = *(const float4*)xp, hi = *(const float4*)(xp + 4);
            union { unsigned short u[8]; uint4 v4; uint2 v2[2]; } t;
            t.u[0] = f2bf(lo.x); t.u[1] = f2bf(lo.y); t.u[2] = f2bf(lo.z); t.u[3] = f2bf(lo.w);
            t.u[4] = f2bf(hi.x); t.u[5] = f2bf(hi.y); t.u[6] = f2bf(hi.z); t.u[7] = f2bf(hi.w);
            *(uint4*)(ain0 + (size_t)b * 5376 + 1232 + j * 8) = t.v4;       // 16B aligned
            int gi = j * 8, tt = gi >> 10, u = gi & 1023;
            unsigned short* d1 = ain1 + (size_t)b * 5376 + tt * 1344 + 308 + u;  // 8B aligned
            *(uint2*)d1 = t.v2[0];
            *(uint2*)(d1 + 4) = t.v2[1];
            return;
        }
        int zi = i - MAIN;                    // zero pads, uint2 (4-short) units
        const int ZU = BDIM * 12;             // per-buffer zero units
        if (zi < ZU) {                        // ain0: cols [5328,5376)
            int b = zi / 12, u = zi % 12;
            *(uint2*)(ain0 + (size_t)b * 5376 + 5328 + u * 4) = make_uint2(0u, 0u);
        } else if (zi < 2 * ZU) {             // ain1: cols [t*1344+1332, +1344)
            zi -= ZU;
            int b = zi / 12, u = zi % 12, tt = u / 3, k = u % 3;
            *(uint2*)(ain1 + (size_t)b * 5376 + tt * 1344 + 1332 + k * 4) = make_uint2(0u, 0u);
        }
        return;
    }
    bid -= PACK_BLOCKS;
    const float* W; unsigned short* dst;
    int I, O, Npad, Kpad, gx, gy, local;
    if (bid < 256)       { W = W4; dst = wbt;           I = 16;   O = 20;  Npad = 20;  Kpad = 32;   gx = 1;  gy = 1;  local = bid; }
    else if (bid < 640)  { W = W3; dst = wbt + 163840;  I = 144;  O = 20;  Npad = 20;  Kpad = 192;  gx = 6;  gy = 1;  local = bid - 256; }
    else if (bid < 1216) { W = W2; dst = wbt + 409600;  I = 336;  O = 77;  Npad = 77;  Kpad = 384;  gx = 12; gy = 3;  local = bid - 640; }
    else                 { W = W1; dst = wbt + 882688;  I = 1332; O = 308; Npad = 320; Kpad = 1344; gx = 42; gy = 10; local = bid - 1216; }
    int per = gx * gy;
    int t = local / per, rem = local % per;
    int by = rem / gx, bx = rem % gx;
    cvt_w_body(W + (size_t)t * I * O, dst + (size_t)t * Npad * Kpad,
               I, O, Npad, Kpad, bx * 32, by * 32, threadIdx.x);
}

__global__ __launch_bounds__(256) void cvt_w(const float* __restrict__ W,
                                             unsigned short* __restrict__ WbT,
                                             int I, int O, int Npad, int Kpad) {
    cvt_w_body(W + (size_t)blockIdx.z * I * O, WbT + (size_t)blockIdx.z * Npad * Kpad,
               I, O, Npad, Kpad, blockIdx.x * 32, blockIdx.y * 32, threadIdx.x);
}

// ---- small-stage GEMM + fused column stats (chunk = blockIdx.y, 32 chunks of 64 rows)
template <int BN, int BK>
__global__ __launch_bounds__(256) void gemm_small(
    const unsigned short* __restrict__ actb,  // [B][T*C] bf16 (null if C==0)
    const unsigned short* __restrict__ xg,    // bf16 x copy, row stride 5376
    const unsigned short* __restrict__ WbT,   // [T][O][Kpad] bf16
    const float* __restrict__ bias,
    unsigned short* __restrict__ h,           // [B][hstride]
    float* __restrict__ sp,                   // [32][2*TO] col-sum partials
    int T, int I, int O, int C, int Gs, int Kpad, int hstride, int TO)
{
    const int t  = blockIdx.z;
    const int b0 = blockIdx.y * 64;
    const int o0 = blockIdx.x * BN;
    const int tid = threadIdx.x;
    const int lane = tid & 63;
    const int w = tid >> 6;
    const int l15 = lane & 15;
    const int quad = lane >> 4;

    constexpr int NF = BN / 32;
    const int wm = (w & 1) * 32;
    const int wn = (w >> 1) * (BN / 2);

    __shared__ __align__(16) unsigned short As[64][BK + 8];
    __shared__ __align__(16) unsigned short Bs[BN][BK + 8];
    __shared__ float ldsS[2][BN], ldsS2[2][BN];

    float4v acc[2][NF];
    #pragma unroll
    for (int a = 0; a < 2; a++)
        #pragma unroll
        for (int b = 0; b < NF; b++)
            acc[a][b] = (float4v){0.f, 0.f, 0.f, 0.f};

    constexpr int GR = BK / 8;
    constexpr int AG = 64 * GR;
    constexpr int BG = BN * GR;
    const size_t actRow = (size_t)T * C;

    for (int k0 = 0; k0 < Kpad; k0 += BK) {
        #pragma unroll
        for (int g = tid; g < AG; g += 256) {
            const int r = g / GR, c8 = g % GR;
            const int k = k0 + c8 * 8;
            const int b = b0 + r;
            uint4 v;
            if (k + 8 <= C) {
                v = *(const uint4*)(actb + (size_t)b * actRow + (size_t)t * C + k);
            } else if (k >= I) {
                v = make_uint4(0u, 0u, 0u, 0u);
            } else {
                v = *(const uint4*)(xg + (size_t)b * 5376 + (size_t)t * Gs + (k - C));
            }
            *(uint4*)&As[r][c8 * 8] = v;
        }
        #pragma unroll
        for (int g = tid; g < BG; g += 256) {
            const int n = g / GR, c8 = g % GR;
            const int o = o0 + n;
            uint4 v = make_uint4(0u, 0u, 0u, 0u);
            if (o < O)
                v = *(const uint4*)(WbT + ((size_t)t * O + o) * Kpad + k0 + c8 * 8);
            *(uint4*)&Bs[n][c8 * 8] = v;
        }
        __syncthreads();
        #pragma unroll
        for (int ks = 0; ks < BK / 32; ks++) {
            const int koff = ks * 32 + quad * 8;
            short8 a0 = *(const short8*)&As[wm + l15][koff];
            short8 a1 = *(const short8*)&As[wm + 16 + l15][koff];
            #pragma unroll
            for (int fn = 0; fn < NF; fn++) {
                short8 bf = *(const short8*)&Bs[wn + fn * 16 + l15][koff];
                acc[0][fn] = __builtin_amdgcn_mfma_f32_16x16x32_bf16(a0, bf, acc[0][fn], 0, 0, 0);
                acc[1][fn] = __builtin_amdgcn_mfma_f32_16x16x32_bf16(a1, bf, acc[1][fn], 0, 0, 0);
            }
        }
        __syncthreads();
    }

    // epilogue + per-thread column partial sums (fp32, pre-rounding)
    float csum[NF], csum2[NF];
    #pragma unroll
    for (int fn = 0; fn < NF; fn++) { csum[fn] = 0.f; csum2[fn] = 0.f; }
    #pragma unroll
    for (int fm = 0; fm < 2; fm++)
        #pragma unroll
        for (int fn = 0; fn < NF; fn++)
            #pragma unroll
            for (int r = 0; r < 4; r++) {
                int m = wm + fm * 16 + quad * 4 + r;
                int o = o0 + wn + fn * 16 + l15;
                if (o < O) {
                    float v = acc[fm][fn][r] + bias[t * O + o];
                    h[(size_t)(b0 + m) * hstride + (size_t)t * O + o] = f2bf(v);
                    csum[fn] += v; csum2[fn] += v * v;
                }
            }
    #pragma unroll
    for (int fn = 0; fn < NF; fn++) {
        csum[fn]  += __shfl_xor(csum[fn], 16, 64);
        csum[fn]  += __shfl_xor(csum[fn], 32, 64);
        csum2[fn] += __shfl_xor(csum2[fn], 16, 64);
        csum2[fn] += __shfl_xor(csum2[fn], 32, 64);
    }
    if (quad == 0) {
        #pragma unroll
        for (int fn = 0; fn < NF; fn++) {
            ldsS[w & 1][wn + fn * 16 + l15]  = csum[fn];
            ldsS2[w & 1][wn + fn * 16 + l15] = csum2[fn];
        }
    }
    __syncthreads();
    if (tid < BN && o0 + tid < O) {
        int col = t * O + o0 + tid;
        size_t base = (size_t)blockIdx.y * 2 * TO;
        sp[base + col]      = ldsS[0][tid] + ldsS[1][tid];
        sp[base + TO + col] = ldsS2[0][tid] + ldsS2[1][tid];
    }
}

// ---- big-stage GEMM (s1/s0): 128-row tile, BK=32, XCD-swizzled 1D grid.
// A: global_load_lds -> dbuf swizzled LDS (slot = row*4+pos, pos = kg^((row>>1)&3)).
// B: DIRECT global->register, double-buffered one K-step ahead (WbT tile is
// 0.34MB, L2-resident; removes 24KB/step of LDS traffic -- the pipe that was
// the per-step floor). Prefetch issued at step start; consumed only after the
// next __syncthreads (which drains vmcnt) -> full compute phase of cover.
template <int BN>
__global__ __launch_bounds__(256) void gemm_split(
    const unsigned short* __restrict__ A,     // [2048][aStride] bf16 (zero-padded)
    const unsigned short* __restrict__ WbT,   // [T][Npad][Kpad] bf16 (zero-padded)
    float* __restrict__ partial,              // [KS][2048][TNpad]
    int aStride, int tStride, int Kpad, int Npad, int KS, int TNpad,
    int nTiles, int TKS)
{
    const int tid = threadIdx.x;
    const int lane = tid & 63, w = tid >> 6;
    const int l15 = lane & 15, quad = lane >> 4;

    // swizzled decode
    const int id = blockIdx.x;
    const int c = id & 7;
    const int tmp = id >> 3;
    const int n = tmp % nTiles;
    const int q = tmp / nTiles;
    const int group = q * 8 + c;
    const int b0 = (group / TKS) * 128;
    const int rem = group % TKS;
    const int t = rem / KS;
    const int ksIdx = rem - t * KS;
    const int n0 = n * BN;

    __shared__ __align__(16) unsigned short As[2][128 * 32];   // 2 x 8 KB (B has no LDS)

    const int S = Kpad >> 5;
    const int qb = S / KS, rb = S % KS;
    const int beg = ksIdx * qb + (ksIdx < rb ? ksIdx : rb);
    const int cnt = qb + (ksIdx < rb ? 1 : 0);

    constexpr int NF = BN / 32;
    const int wm = (w & 1) * 64;
    const int wn = (w >> 1) * (BN / 2);

    float4v acc[4][NF];
    #pragma unroll
    for (int a = 0; a < 4; a++)
        #pragma unroll
        for (int b = 0; b < NF; b++)
            acc[a][b] = (float4v){0.f, 0.f, 0.f, 0.f};

    // A staging: 512 granule-slots, 2 calls/wave
    const unsigned short* aSrc[2];
    int aOff[2];
    #pragma unroll
    for (int j = 0; j < 2; j++) {
        int s = (w * 2 + j) * 64 + lane;
        int r = s >> 2, kg = (s & 3) ^ ((r >> 1) & 3);
        aSrc[j] = A + (size_t)(b0 + r) * aStride + (size_t)t * tStride + kg * 8;
        aOff[j] = (w * 2 + j) * 512;           // shorts
    }
    // B: per-wave fragment base pointers (row = n0+wn+fn*16+l15, k = quad*8 within
    // each 32-short window; identical values/layout to the old LDS-staged frags).
    const unsigned short* bPtr[NF];
    #pragma unroll
    for (int fn = 0; fn < NF; fn++)
        bPtr[fn] = WbT + ((size_t)t * Npad + n0 + wn + fn * 16 + l15) * Kpad
                 + (size_t)(beg << 5) + quad * 8;

    short8 bcur[NF], bnxt[NF];

    // prologue: stage A step 0 into buf 0; load B step 0 into regs
    {
        const int k0 = beg << 5;
        #pragma unroll
        for (int j = 0; j < 2; j++)      stage16(aSrc[j] + k0, &As[0][aOff[j]], lane);
        #pragma unroll
        for (int fn = 0; fn < NF; fn++)  bcur[fn] = *(const short8*)(bPtr[fn]);
    }

    for (int s = 0; s < cnt; s++) {
        const int cur = s & 1;
        __syncthreads();   // drains A cur-buf loads + B prefetch + prev compute
        if (s + 1 < cnt) {
            const int k1 = (beg + s + 1) << 5;
            #pragma unroll
            for (int j = 0; j < 2; j++)      stage16(aSrc[j] + k1, &As[cur ^ 1][aOff[j]], lane);
            #pragma unroll
            for (int fn = 0; fn < NF; fn++)  bnxt[fn] = *(const short8*)(bPtr[fn] + ((s + 1) << 5));
        }
        short8 af[4];
        #pragma unroll
        for (int fm = 0; fm < 4; fm++) {
            int m = wm + fm * 16 + l15;
            int pos = quad ^ ((m >> 1) & 3);
            af[fm] = *(const short8*)&As[cur][(m * 4 + pos) * 8];
        }
        #pragma unroll
        for (int fm = 0; fm < 4; fm++)
            #pragma unroll
            for (int fn = 0; fn < NF; fn++)
                acc[fm][fn] = __builtin_amdgcn_mfma_f32_16x16x32_bf16(af[fm], bcur[fn], acc[fm][fn], 0, 0, 0);
        if (s + 1 < cnt) {
            #pragma unroll
            for (int fn = 0; fn < NF; fn++)  bcur[fn] = bnxt[fn];
        }
    }

    const size_t pBase = ((size_t)ksIdx * BDIM + b0) * TNpad + (size_t)t * Npad + n0;
    #pragma unroll
    for (int fm = 0; fm < 4; fm++)
        #pragma unroll
        for (int r = 0; r < 4; r++) {
            const int m = wm + fm * 16 + quad * 4 + r;
            float* prow = partial + pBase + (size_t)m * TNpad + wn;
            #pragma unroll
            for (int fn = 0; fn < NF; fn++)
                prow[fn * 16 + l15] = acc[fm][fn][r];
        }
}

// ---- fused split-K reduce + bias + bf16 h store + per-chunk stats partials ----
__global__ __launch_bounds__(256) void reduce_bias_stats(
    const float* __restrict__ partial, const float* __restrict__ bias,
    unsigned short* __restrict__ h, float* __restrict__ sp,
    int T, int O, int Npad, int KS, int hstride, int TO)
{
    __shared__ float redS[4][64], redS2[4][64];
    const int colL = threadIdx.x & 63;
    const int cr = threadIdx.x >> 6;
    const int col = blockIdx.x * 64 + colL;
    const int chunk = blockIdx.y;
    float s = 0.f, s2 = 0.f;
    if (col < TO) {
        int t = col / O, o = col - t * O;
        const size_t TNpad = (size_t)T * Npad;
        const size_t pcol = (size_t)t * Npad + o;
        const float bv = bias[col];
        const int row0 = chunk * 128 + cr * 32;
        for (int r = 0; r < 32; r++) {
            const int row = row0 + r;
            const float* p = partial + (size_t)row * TNpad + pcol;
            float v = bv;
            for (int ks = 0; ks < KS; ks++) v += p[(size_t)ks * BDIM * TNpad];
            h[(size_t)row * hstride + col] = f2bf(v);
            s += v; s2 += v * v;
        }
    }
    redS[cr][colL] = s; redS2[cr][colL] = s2;
    __syncthreads();
    if (cr == 0 && col < TO) {
        float ts  = redS[0][colL] + redS[1][colL] + redS[2][colL] + redS[3][colL];
        float ts2 = redS2[0][colL] + redS2[1][colL] + redS2[2][colL] + redS2[3][colL];
        sp[(size_t)chunk * 2 * TO + col] = ts;
        sp[(size_t)chunk * 2 * TO + TO + col] = ts2;
    }
}

// ---- fold NC chunk partials -> per-col scale/shift ----
__global__ __launch_bounds__(256) void bn_scaleN(const float* __restrict__ sp,
                                                 const float* __restrict__ g,
                                                 const float* __restrict__ bb,
                                                 float* __restrict__ ss, int TO, int NC) {
    int col = blockIdx.x * 256 + threadIdx.x;
    if (col >= TO) return;
    float s = 0.f, s2 = 0.f;
    for (int c = 0; c < NC; c++) {
        s  += sp[(size_t)c * 2 * TO + col];
        s2 += sp[(size_t)c * 2 * TO + TO + col];
    }
    float mu = s * (1.f / BDIM);
    float var = s2 * (1.f / BDIM) - mu * mu;  // biased, matches jnp.var
    float scale = rsqrtf(var + 1e-5f) * g[col];
    ss[col] = scale;
    ss[TO + col] = bb[col] - mu * scale;
}

// ---- vectorized BN+tanh+head for O=20 in-place stages (s4/s3) ----
template <int GPT>
__global__ __launch_bounds__(256) void bn_tanh_head_vec(
    unsigned short* hact, const float* __restrict__ ss,
    const float* __restrict__ hw, const float* __restrict__ hb,
    float* __restrict__ out,
    int T, int rowGran, int RPB, int hstride, int head_off)
{
    __shared__ float headAcc[256];
    const int tid = threadIdx.x;
    headAcc[tid] = 0.f;
    __syncthreads();
    const int b0 = blockIdx.x * RPB;

    uint2 hv[GPT];
    #pragma unroll
    for (int j = 0; j < GPT; j++) {
        int G = tid + j * 256;
        int r = G / rowGran, gg = G % rowGran;
        hv[j] = *(const uint2*)(hact + (size_t)(b0 + r) * hstride + gg * 4);
    }
    #pragma unroll
    for (int j = 0; j < GPT; j++) {
        int G = tid + j * 256;
        int r = G / rowGran, gg = G % rowGran;
        int c = gg * 4;
        float4 sc = *(const float4*)(ss + c);
        float4 sh = *(const float4*)(ss + hstride + c);
        float4 w4 = *(const float4*)(hw + c);
        union { unsigned short u[4]; uint2 v; } iv, ov;
        iv.v = hv[j];
        float a0 = fast_tanh(bf2f(iv.u[0]) * sc.x + sh.x);
        float a1 = fast_tanh(bf2f(iv.u[1]) * sc.y + sh.y);
        float a2 = fast_tanh(bf2f(iv.u[2]) * sc.z + sh.z);
        float a3 = fast_tanh(bf2f(iv.u[3]) * sc.w + sh.w);
        ov.u[0] = f2bf(a0); ov.u[1] = f2bf(a1); ov.u[2] = f2bf(a2); ov.u[3] = f2bf(a3);
        *(uint2*)(hact + (size_t)(b0 + r) * hstride + c) = ov.v;
        float partial = a0 * w4.x + a1 * w4.y + a2 * w4.z + a3 * w4.w;
        int t = gg / 5;
        atomicAdd(&headAcc[r * T + t], partial);
    }
    __syncthreads();
    if (tid < RPB * T) {
        int r = tid / T, t = tid % T;
        out[(size_t)(b0 + r) * OUTW + head_off + t] = headAcc[tid] + hb[t];
    }
}

// ---- BN + tanh + strided act store + head — WAVE variant ----
__global__ __launch_bounds__(256) void bn_tanh_head(
    const unsigned short* __restrict__ h, const float* __restrict__ ss,
    const float* __restrict__ hw, const float* __restrict__ hb,
    unsigned short* __restrict__ actOut, float* __restrict__ out,
    int T, int O, int hstride, int aRow, int GT, int GS, int head_off, int TO)
{
    int wid  = (blockIdx.x * 256 + threadIdx.x) >> 6;
    int lane = threadIdx.x & 63;
    int b = wid / T;
    int t = wid % T;
    const size_t hbase = (size_t)b * hstride + (size_t)t * O;
    const size_t abase = (size_t)b * aRow + (size_t)(t / GT) * GS + (size_t)(t % GT) * O;
    float hsum = 0.f;
    for (int o = lane; o < O; o += 64) {
        int col = t * O + o;
        float a = fast_tanh(bf2f(h[hbase + o]) * ss[col] + ss[TO + col]);
        if (actOut) actOut[abase + o] = f2bf(a);
        hsum += a * hw[col];
    }
    #pragma unroll
    for (int off = 32; off > 0; off >>= 1) hsum += __shfl_down(hsum, off, 64);
    if (lane == 0) out[(size_t)b * OUTW + head_off + t] = hsum + hb[t];
}

extern "C" void kernel_launch(void* const* d_in, const int* in_sizes, int n_in,
                              void* d_out, int out_size, void* d_ws, size_t ws_size,
                              hipStream_t stream)
{
    const float* x = (const float*)d_in[0];
    float* out = (float*)d_out;
    char* ws = (char*)d_ws;

    // ws layout (bytes)
    unsigned short* wbt  = (unsigned short*)(ws);              // 13,762,560
    unsigned short* ain0 = (unsigned short*)(ws + 13762560);   // 22,020,096 (2048x5376)
    unsigned short* bufA = (unsigned short*)(ws + 35782656);   // 20,971,520
    unsigned short* bufB = (unsigned short*)(ws + 56754176);   //  5,242,880
    unsigned short* ain1 = (unsigned short*)(ws + 61997056);   // 22,020,096
    unsigned short* bufC = (unsigned short*)(ws + 84017152);   //  5,046,272
    float*          ss   = (float*)(ws + 89063424);            //     40,960
    float*          sp0  = (float*)(ws + 89104384);            //    157,312 (16x2x1229)
    // overlays (all verified dead at use time):
    float* partial = (float*)(ws + 35782656);   // s1: 21 MB (=bufA), s0: 41.9 MB (bufA..ain1 head)
    float* sp4 = (float*)bufC;                  // 32x2x5120x4 = 1.31 MB (bufC free pre-s2)
    float* sp3 = (float*)bufC;                  // 0.33 MB
    float* sp2 = (float*)bufA;                  // 0.32 MB (act4 dead after s3 gemm)
    float* sp1 = (float*)bufB;                  // 0.32 MB (act3 dead after s2 gemm)
    unsigned short* xg = ain0 + 1232;           // full bf16 x copy, row stride 5376

    const float* W4 = (const float*)d_in[1];  const float* b4 = (const float*)d_in[2];
    const float* g4 = (const float*)d_in[3];  const float* bb4 = (const float*)d_in[4];
    const float* hw4 = (const float*)d_in[5]; const float* hb4 = (const float*)d_in[6];
    const float* W3 = (const float*)d_in[7];  const float* b3 = (const float*)d_in[8];
    const float* g3 = (const float*)d_in[9];  const float* bb3 = (const float*)d_in[10];
    const float* hw3 = (const float*)d_in[11]; const float* hb3 = (const float*)d_in[12];
    const float* W2 = (const float*)d_in[13]; const float* b2 = (const float*)d_in[14];
    const float* g2 = (const float*)d_in[15]; const float* bb2 = (const float*)d_in[16];
    const float* hw2 = (const float*)d_in[17]; const float* hb2 = (const float*)d_in[18];
    const float* W1 = (const float*)d_in[19]; const float* b1 = (const float*)d_in[20];
    const float* g1 = (const float*)d_in[21]; const float* bb1 = (const float*)d_in[22];
    const float* hw1 = (const float*)d_in[23]; const float* hb1 = (const float*)d_in[24];
    const float* W0 = (const float*)d_in[25]; const float* b0_ = (const float*)d_in[26];
    const float* g0 = (const float*)d_in[27]; const float* bb0 = (const float*)d_in[28];
    const float* hw0 = (const float*)d_in[29]; const float* hb0 = (const float*)d_in[30];

    // 1: fused x pack + weight conversions (s4..s1)
    pack_cvt<<<PACK_BLOCKS + 2896, 256, 0, stream>>>(x, ain0, ain1, W4, W3, W2, W1, wbt);

    // s4: T=256 I=16 O=20 Kpad=32, WbT @0
    gemm_small<32, 32><<<dim3(1, 32, 256), 256, 0, stream>>>(nullptr, xg, wbt, b4, bufA,
                                                             sp4, 256, 16, 20, 0, 16, 32, 5120, 5120);
    bn_scaleN<<<20, 256, 0, stream>>>(sp4, g4, bb4, ss, 5120, 32);
    bn_tanh_head_vec<5><<<BDIM, 256, 0, stream>>>(bufA, ss, hw4, hb4, out, 256, 1280, 1, 5120, 0);

    // s3: T=64 I=144 O=20 Kpad=192, WbT @163840
    gemm_small<32, 64><<<dim3(1, 32, 64), 256, 0, stream>>>(bufA, xg, wbt + 163840, b3, bufB,
                                                            sp3, 64, 144, 20, 80, 64, 192, 1280, 1280);
    bn_scaleN<<<5, 256, 0, stream>>>(sp3, g3, bb3, ss, 1280, 32);
    bn_tanh_head_vec<5><<<BDIM / 4, 256, 0, stream>>>(bufB, ss, hw3, hb3, out, 64, 320, 4, 1280, 256);

    // s2: T=16 I=336 O=77 Kpad=384, WbT @409600
    gemm_small<64, 64><<<dim3(2, 32, 16), 256, 0, stream>>>(bufB, xg, wbt + 409600, b2, bufC,
                                                            sp2, 16, 336, 77, 80, 256, 384, 1232, 1232);
    bn_scaleN<<<5, 256, 0, stream>>>(sp2, g2, bb2, ss, 1232, 32);
    bn_tanh_head<<<BDIM * 16 / 4, 256, 0, stream>>>(bufC, ss, hw2, hb2,
                                                    ain1, out, 16, 77, 1232, 5376, 4, 1344, 320, 1232);

    // s1: T=4 I=1332 O=308 Kpad=1344 Npad=320 KS=2, WbT @882688
    // swizzled 1D grid: nTiles=5, TKS=T*KS=8, blocks = 5*16*8 = 640
    gemm_split<64><<<640, 256, 0, stream>>>(ain1, wbt + 882688, partial,
                                            5376, 1344, 1344, 320, 2, 1280, 5, 8);
    cvt_w<<<dim3(168, 40, 1), 256, 0, stream>>>(W0, wbt, 5328, 1229, 1280, 5376);  // overlaps s1 tail
    reduce_bias_stats<<<dim3(20, 16), 256, 0, stream>>>(partial, b1, bufC, sp1,
                                                        4, 308, 320, 2, 1232, 1232);
    bn_scaleN<<<5, 256, 0, stream>>>(sp1, g1, bb1, ss, 1232, 16);
    bn_tanh_head<<<BDIM * 4 / 4, 256, 0, stream>>>(bufC, ss, hw1, hb1,
                                                   ain0, out, 4, 308, 1232, 5376, 4, 0, 336, 1232);

    // s0: T=1 I=5328 O=1229 Kpad=5376 Npad=1280 KS=4
    // swizzled 1D grid: nTiles=10, TKS=4, blocks = 10*16*4 = 640
    gemm_split<128><<<640, 256, 0, stream>>>(ain0, wbt, partial,
                                             5376, 0, 5376, 1280, 4, 1280, 10, 4);
    reduce_bias_stats<<<dim3(20, 16), 256, 0, stream>>>(partial, b0_, bufC, sp0,
                                                        1, 1229, 1280, 4, 1232, 1229);
    bn_scaleN<<<5, 256, 0, stream>>>(sp0, g0, bb0, ss, 1229, 16);
    bn_tanh_head<<<BDIM / 4, 256, 0, stream>>>(bufC, ss, hw0, hb0,
                                               nullptr, out, 1, 1229, 1232, 1232, 1, 0, 340, 1229);
}

// Round 4
// 437.208 us; speedup vs baseline: 3.9954x; 1.1330x over previous
//
#include <hip/hip_runtime.h>
#include <hip/hip_bf16.h>

// DCell forward, bf16-MFMA. Round-12:
//  * gemm_split FULLY REVERTED to round-8 body (B via LDS, 2-buf, 1 sync).
//    Three schedule/operand experiments (r9 depth-2 vmcnt, r10 fences, r11
//    B-direct-to-reg) all regressed -> r8 body is the local optimum; frozen.
//  * s4 stage restructured (the lever this round): h4 (21MB) never
//    materialized. Pass1 s4_fused<false>: MFMA h in-register, column stats
//    only (shuffle-reduce -> sp). Pass2 s4_fused<true>: recompute identical h,
//    BN(scale,shift with bias folded)+tanh, act4 via LDS-transposed coalesced
//    stores, head sums in-wave (no atomics) -> out. Replaces gemm_small-s4 +
//    bn_tanh_head_vec-s4; s4 traffic 79MB -> ~53MB (16 L3-hot).
//  * everything else = round-8 structure (5x bn_scaleN tiny launches kept:
//    round-10 proved cross-block fold fences cost an L2 writeback each).
// Swizzle: id = c + 8*(q*nTiles + n), group = q*8+c = (b-tile*T*KS + t*KS + ks).
// Stage cfg (T,I,O,C,Gs): s4(256,16,20,0,16) s3(64,144,20,80,64)
//  s2(16,336,77,80,256) s1(4,1332,308,308,1024) s0(1,5328,1229,1232,4096)

#define BDIM 2048
#define OUTW 341

typedef __attribute__((ext_vector_type(8))) short short8;
typedef __attribute__((ext_vector_type(4))) float float4v;

static __device__ __forceinline__ unsigned short f2bf(float f) {
    union { float f; unsigned u; } c{f};
    unsigned r = c.u + 0x7FFF + ((c.u >> 16) & 1);  // RNE
    return (unsigned short)(r >> 16);
}
static __device__ __forceinline__ float bf2f(unsigned short s) {
    union { unsigned u; float f; } c{(unsigned)s << 16};
    return c.f;
}

static __device__ __forceinline__ float fast_tanh(float x) {
    float ax = __builtin_fabsf(x);
    float e  = __builtin_amdgcn_exp2f(ax * 2.8853900817779268f);  // e^{2|x|}
    float r  = 1.f - 2.f * __builtin_amdgcn_rcpf(e + 1.f);
    return __builtin_copysignf(r, x);
}

// async global->LDS, 16B/lane: wave-uniform base + lane*16.
static __device__ __forceinline__ void stage16(const void* g, void* ldsBase, int lane) {
#if __has_builtin(__builtin_amdgcn_global_load_lds)
    __builtin_amdgcn_global_load_lds(
        (const __attribute__((address_space(1))) unsigned int*)(uintptr_t)g,
        (__attribute__((address_space(3))) unsigned int*)(unsigned int)(uintptr_t)ldsBase,
        16, 0, 0);
#else
    *(uint4*)((char*)ldsBase + lane * 16) = *(const uint4*)g;
#endif
}

// ---- W[t][I][O] fp32 -> WbT[t][Npad][Kpad] bf16 core ----
static __device__ __forceinline__ void cvt_w_body(const float* Wt, unsigned short* dst,
                                                  int I, int O, int Npad, int Kpad,
                                                  int i0, int o0, int tid) {
    __shared__ unsigned short tile[32][33];
    const int c = tid & 31, r0 = tid >> 5;
    #pragma unroll
    for (int rr = 0; rr < 4; rr++) {
        int i = i0 + r0 + rr * 8, o = o0 + c;
        float v = (i < I && o < O) ? Wt[(size_t)i * O + o] : 0.f;
        tile[r0 + rr * 8][c] = f2bf(v);
    }
    __syncthreads();
    #pragma unroll
    for (int rr = 0; rr < 4; rr++) {
        int o = o0 + r0 + rr * 8, k = i0 + c;
        if (o < Npad) dst[(size_t)o * Kpad + k] = tile[c][r0 + rr * 8];
    }
}

// ---- fused: x pack (read once -> bf16 into ain0/ain1 + zero pads) AND
//      W4..W1 -> bf16 WbT conversion. Disjoint inputs/outputs, no ordering.
#define PACK_BLOCKS ((BDIM * 512 + BDIM * 24 + 255) / 256)   // 4288
__global__ __launch_bounds__(256) void pack_cvt(const float* __restrict__ x,
                                                unsigned short* __restrict__ ain0,
                                                unsigned short* __restrict__ ain1,
                                                const float* __restrict__ W4,
                                                const float* __restrict__ W3,
                                                const float* __restrict__ W2,
                                                const float* __restrict__ W1,
                                                unsigned short* __restrict__ wbt) {
    int bid = blockIdx.x;
    if (bid < PACK_BLOCKS) {
        const int MAIN = BDIM * 512;          // 8-float units
        int i = bid * 256 + threadIdx.x;
        if (i < MAIN) {
            int b = i >> 9, j = i & 511;
            const float* xp = x + (size_t)b * 4096 + j * 8;
            float4 lo = *(const float4*)xp, hi = *(const float4*)(xp + 4);
            union { unsigned short u[8]; uint4 v4; uint2 v2[2]; } t;
            t.u[0] = f2bf(lo.x); t.u[1] = f2bf(lo.y); t.u[2] = f2bf(lo.z); t.u[3] = f2bf(lo.w);
            t.u[4] = f2bf(hi.x); t.u[5] = f2bf(hi.y); t.u[6] = f2bf(hi.z); t.u[7] = f2bf(hi.w);
            *(uint4*)(ain0 + (size_t)b * 5376 + 1232 + j * 8) = t.v4;       // 16B aligned
            int gi = j * 8, tt = gi >> 10, u = gi & 1023;
            unsigned short* d1 = ain1 + (size_t)b * 5376 + tt * 1344 + 308 + u;  // 8B aligned
            *(uint2*)d1 = t.v2[0];
            *(uint2*)(d1 + 4) = t.v2[1];
            return;
        }
        int zi = i - MAIN;                    // zero pads, uint2 (4-short) units
        const int ZU = BDIM * 12;             // per-buffer zero units
        if (zi < ZU) {                        // ain0: cols [5328,5376)
            int b = zi / 12, u = zi % 12;
            *(uint2*)(ain0 + (size_t)b * 5376 + 5328 + u * 4) = make_uint2(0u, 0u);
        } else if (zi < 2 * ZU) {             // ain1: cols [t*1344+1332, +1344)
            zi -= ZU;
            int b = zi / 12, u = zi % 12, tt = u / 3, k = u % 3;
            *(uint2*)(ain1 + (size_t)b * 5376 + tt * 1344 + 1332 + k * 4) = make_uint2(0u, 0u);
        }
        return;
    }
    bid -= PACK_BLOCKS;
    const float* W; unsigned short* dst;
    int I, O, Npad, Kpad, gx, gy, local;
    if (bid < 256)       { W = W4; dst = wbt;           I = 16;   O = 20;  Npad = 20;  Kpad = 32;   gx = 1;  gy = 1;  local = bid; }
    else if (bid < 640)  { W = W3; dst = wbt + 163840;  I = 144;  O = 20;  Npad = 20;  Kpad = 192;  gx = 6;  gy = 1;  local = bid - 256; }
    else if (bid < 1216) { W = W2; dst = wbt + 409600;  I = 336;  O = 77;  Npad = 77;  Kpad = 384;  gx = 12; gy = 3;  local = bid - 640; }
    else                 { W = W1; dst = wbt + 882688;  I = 1332; O = 308; Npad = 320; Kpad = 1344; gx = 42; gy = 10; local = bid - 1216; }
    int per = gx * gy;
    int t = local / per, rem = local % per;
    int by = rem / gx, bx = rem % gx;
    cvt_w_body(W + (size_t)t * I * O, dst + (size_t)t * Npad * Kpad,
               I, O, Npad, Kpad, bx * 32, by * 32, threadIdx.x);
}

__global__ __launch_bounds__(256) void cvt_w(const float* __restrict__ W,
                                             unsigned short* __restrict__ WbT,
                                             int I, int O, int Npad, int Kpad) {
    cvt_w_body(W + (size_t)blockIdx.z * I * O, WbT + (size_t)blockIdx.z * Npad * Kpad,
               I, O, Npad, Kpad, blockIdx.x * 32, blockIdx.y * 32, threadIdx.x);
}

// ---- s4 fused pair: 1024 blocks = 32 col-groups (8 t's = 160 cols) x 32
// row-chunks (64 rows). h computed in-register via MFMA on wbt-s4 (bf16),
// identical in both passes -> stats exactly consistent with act.
// WITH_ACT=false: column stats only -> sp[rc][2][5120].
// WITH_ACT=true : BN+tanh -> act4 (LDS transpose, coalesced), head -> out.
template <bool WITH_ACT>
__global__ __launch_bounds__(256) void s4_fused(
    const unsigned short* __restrict__ xg,   // genes, row stride 5376
    const unsigned short* __restrict__ wbt4, // [256][20][32] bf16
    const float* __restrict__ b4,            // flat [5120]
    const float* __restrict__ ss,            // [2][5120]      (act pass)
    const float* __restrict__ hw,            // flat [5120]    (act pass)
    const float* __restrict__ hb,            // [256]          (act pass)
    unsigned short* __restrict__ act,        // [2048][5120]   (act pass)
    float* __restrict__ sp,                  // [32][2][5120]  (stats pass)
    float* __restrict__ out)                 // (act pass)
{
    const int cg = blockIdx.x & 31;
    const int rc = blockIdx.x >> 5;
    const int t0 = cg * 8, b0 = rc * 64;
    const int tid = threadIdx.x;
    const int lane = tid & 63, w = tid >> 6;
    const int l15 = lane & 15, quad = lane >> 4;

    // stride 168 shorts = 84 dwords: frag reads (row stride) land 2 lanes/bank.
    __shared__ __align__(16) unsigned short xs[64][168];

    // stage 64 rows x 128 genes, zero cols [128,144) (A quads 2-3 of t=7 read
    // there; B is zero for k>=16 so product is 0 -- just must be finite).
    #pragma unroll
    for (int j = 0; j < 4; j++) {
        int i = tid + j * 256;
        int r = i >> 4, gg = i & 15;
        *(uint4*)&xs[r][gg * 8] =
            *(const uint4*)(xg + (size_t)(b0 + r) * 5376 + t0 * 16 + gg * 8);
    }
    if (tid < 128) {
        int r = tid >> 1, gg = 16 + (tid & 1);
        *(uint4*)&xs[r][gg * 8] = make_uint4(0u, 0u, 0u, 0u);
    }
    __syncthreads();

    // wave w owns terms {2w, 2w+1}; 4 m-frags cover all 64 rows; 2 n-frags
    // cover O=20 (cols 20..31 garbage, discarded).
    float4v acc[2][4][2];
    #pragma unroll
    for (int a = 0; a < 2; a++)
        #pragma unroll
        for (int b = 0; b < 4; b++)
            #pragma unroll
            for (int c = 0; c < 2; c++)
                acc[a][b][c] = (float4v){0.f, 0.f, 0.f, 0.f};

    #pragma unroll
    for (int ti = 0; ti < 2; ti++) {
        const int lt = w * 2 + ti;
        const int t = t0 + lt;
        short8 bf[2];
        #pragma unroll
        for (int nf = 0; nf < 2; nf++)
            bf[nf] = *(const short8*)(wbt4 + ((size_t)t * 20 + nf * 16 + l15) * 32 + quad * 8);
        #pragma unroll
        for (int mf = 0; mf < 4; mf++) {
            short8 a = *(const short8*)&xs[mf * 16 + l15][lt * 16 + quad * 8];
            #pragma unroll
            for (int nf = 0; nf < 2; nf++)
                acc[ti][mf][nf] = __builtin_amdgcn_mfma_f32_16x16x32_bf16(a, bf[nf], acc[ti][mf][nf], 0, 0, 0);
        }
    }

    if (!WITH_ACT) {
        // column stats over this block's 64 rows (bias included, pre-rounding)
        #pragma unroll
        for (int ti = 0; ti < 2; ti++) {
            const int lt = w * 2 + ti;
            #pragma unroll
            for (int nf = 0; nf < 2; nf++) {
                const int o = nf * 16 + l15;
                const int col = (t0 + lt) * 20 + o;
                const bool valid = (o < 20);
                const float bias = valid ? b4[col] : 0.f;
                float s = 0.f, s2 = 0.f;
                #pragma unroll
                for (int mf = 0; mf < 4; mf++)
                    #pragma unroll
                    for (int r = 0; r < 4; r++) {
                        float v = acc[ti][mf][nf][r] + bias;
                        s += v; s2 += v * v;
                    }
                s  += __shfl_xor(s, 16, 64);  s  += __shfl_xor(s, 32, 64);
                s2 += __shfl_xor(s2, 16, 64); s2 += __shfl_xor(s2, 32, 64);
                if (quad == 0 && valid) {
                    sp[(size_t)rc * 10240 + col] = s;
                    sp[(size_t)rc * 10240 + 5120 + col] = s2;
                }
            }
        }
    } else {
        __syncthreads();   // all waves done reading xs; reuse as act tile
        #pragma unroll
        for (int ti = 0; ti < 2; ti++) {
            const int lt = w * 2 + ti;
            const int t = t0 + lt;
            float hp[4][4];
            #pragma unroll
            for (int mf = 0; mf < 4; mf++)
                #pragma unroll
                for (int r = 0; r < 4; r++) hp[mf][r] = 0.f;
            #pragma unroll
            for (int nf = 0; nf < 2; nf++) {
                const int o = nf * 16 + l15;
                const int col = t * 20 + o;
                const bool valid = (o < 20);
                const float scale = valid ? ss[col] : 0.f;
                const float shp   = valid ? (b4[col] * scale + ss[5120 + col]) : 0.f;
                const float hwv   = valid ? hw[col] : 0.f;
                #pragma unroll
                for (int mf = 0; mf < 4; mf++)
                    #pragma unroll
                    for (int r = 0; r < 4; r++) {
                        float av = fast_tanh(acc[ti][mf][nf][r] * scale + shp);
                        if (valid)
                            xs[mf * 16 + quad * 4 + r][lt * 20 + o] = f2bf(av);
                        hp[mf][r] += av * hwv;
                    }
            }
            const float hbv = hb[t];
            #pragma unroll
            for (int mf = 0; mf < 4; mf++)
                #pragma unroll
                for (int r = 0; r < 4; r++) {
                    float v = hp[mf][r];
                    v += __shfl_xor(v, 1, 64); v += __shfl_xor(v, 2, 64);
                    v += __shfl_xor(v, 4, 64); v += __shfl_xor(v, 8, 64);
                    if (l15 == 0)
                        out[(size_t)(b0 + mf * 16 + quad * 4 + r) * OUTW + t] = v + hbv;
                }
        }
        __syncthreads();
        // coalesced act copy-out: 64 rows x 160 cols
        #pragma unroll
        for (int j = 0; j < 5; j++) {
            int i = tid + j * 256;
            int r = i / 20, gg = i % 20;
            *(uint4*)(act + (size_t)(b0 + r) * 5120 + cg * 160 + gg * 8) =
                *(uint4*)&xs[r][gg * 8];
        }
    }
}

// ---- small-stage GEMM + fused column stats (chunk = blockIdx.y, 32 chunks of 64 rows)
template <int BN, int BK>
__global__ __launch_bounds__(256) void gemm_small(
    const unsigned short* __restrict__ actb,  // [B][T*C] bf16 (null if C==0)
    const unsigned short* __restrict__ xg,    // bf16 x copy, row stride 5376
    const unsigned short* __restrict__ WbT,   // [T][O][Kpad] bf16
    const float* __restrict__ bias,
    unsigned short* __restrict__ h,           // [B][hstride]
    float* __restrict__ sp,                   // [32][2*TO] col-sum partials
    int T, int I, int O, int C, int Gs, int Kpad, int hstride, int TO)
{
    const int t  = blockIdx.z;
    const int b0 = blockIdx.y * 64;
    const int o0 = blockIdx.x * BN;
    const int tid = threadIdx.x;
    const int lane = tid & 63;
    const int w = tid >> 6;
    const int l15 = lane & 15;
    const int quad = lane >> 4;

    constexpr int NF = BN / 32;
    const int wm = (w & 1) * 32;
    const int wn = (w >> 1) * (BN / 2);

    __shared__ __align__(16) unsigned short As[64][BK + 8];
    __shared__ __align__(16) unsigned short Bs[BN][BK + 8];
    __shared__ float ldsS[2][BN], ldsS2[2][BN];

    float4v acc[2][NF];
    #pragma unroll
    for (int a = 0; a < 2; a++)
        #pragma unroll
        for (int b = 0; b < NF; b++)
            acc[a][b] = (float4v){0.f, 0.f, 0.f, 0.f};

    constexpr int GR = BK / 8;
    constexpr int AG = 64 * GR;
    constexpr int BG = BN * GR;
    const size_t actRow = (size_t)T * C;

    for (int k0 = 0; k0 < Kpad; k0 += BK) {
        #pragma unroll
        for (int g = tid; g < AG; g += 256) {
            const int r = g / GR, c8 = g % GR;
            const int k = k0 + c8 * 8;
            const int b = b0 + r;
            uint4 v;
            if (k + 8 <= C) {
                v = *(const uint4*)(actb + (size_t)b * actRow + (size_t)t * C + k);
            } else if (k >= I) {
                v = make_uint4(0u, 0u, 0u, 0u);
            } else {
                v = *(const uint4*)(xg + (size_t)b * 5376 + (size_t)t * Gs + (k - C));
            }
            *(uint4*)&As[r][c8 * 8] = v;
        }
        #pragma unroll
        for (int g = tid; g < BG; g += 256) {
            const int n = g / GR, c8 = g % GR;
            const int o = o0 + n;
            uint4 v = make_uint4(0u, 0u, 0u, 0u);
            if (o < O)
                v = *(const uint4*)(WbT + ((size_t)t * O + o) * Kpad + k0 + c8 * 8);
            *(uint4*)&Bs[n][c8 * 8] = v;
        }
        __syncthreads();
        #pragma unroll
        for (int ks = 0; ks < BK / 32; ks++) {
            const int koff = ks * 32 + quad * 8;
            short8 a0 = *(const short8*)&As[wm + l15][koff];
            short8 a1 = *(const short8*)&As[wm + 16 + l15][koff];
            #pragma unroll
            for (int fn = 0; fn < NF; fn++) {
                short8 bf = *(const short8*)&Bs[wn + fn * 16 + l15][koff];
                acc[0][fn] = __builtin_amdgcn_mfma_f32_16x16x32_bf16(a0, bf, acc[0][fn], 0, 0, 0);
                acc[1][fn] = __builtin_amdgcn_mfma_f32_16x16x32_bf16(a1, bf, acc[1][fn], 0, 0, 0);
            }
        }
        __syncthreads();
    }

    // epilogue + per-thread column partial sums (fp32, pre-rounding)
    float csum[NF], csum2[NF];
    #pragma unroll
    for (int fn = 0; fn < NF; fn++) { csum[fn] = 0.f; csum2[fn] = 0.f; }
    #pragma unroll
    for (int fm = 0; fm < 2; fm++)
        #pragma unroll
        for (int fn = 0; fn < NF; fn++)
            #pragma unroll
            for (int r = 0; r < 4; r++) {
                int m = wm + fm * 16 + quad * 4 + r;
                int o = o0 + wn + fn * 16 + l15;
                if (o < O) {
                    float v = acc[fm][fn][r] + bias[t * O + o];
                    h[(size_t)(b0 + m) * hstride + (size_t)t * O + o] = f2bf(v);
                    csum[fn] += v; csum2[fn] += v * v;
                }
            }
    #pragma unroll
    for (int fn = 0; fn < NF; fn++) {
        csum[fn]  += __shfl_xor(csum[fn], 16, 64);
        csum[fn]  += __shfl_xor(csum[fn], 32, 64);
        csum2[fn] += __shfl_xor(csum2[fn], 16, 64);
        csum2[fn] += __shfl_xor(csum2[fn], 32, 64);
    }
    if (quad == 0) {
        #pragma unroll
        for (int fn = 0; fn < NF; fn++) {
            ldsS[w & 1][wn + fn * 16 + l15]  = csum[fn];
            ldsS2[w & 1][wn + fn * 16 + l15] = csum2[fn];
        }
    }
    __syncthreads();
    if (tid < BN && o0 + tid < O) {
        int col = t * O + o0 + tid;
        size_t base = (size_t)blockIdx.y * 2 * TO;
        sp[base + col]      = ldsS[0][tid] + ldsS[1][tid];
        sp[base + TO + col] = ldsS2[0][tid] + ldsS2[1][tid];
    }
}

// ---- big-stage GEMM (s1/s0): 128-row tile, BK=32, dbuf LDS, XCD-swizzled 1D grid
// (round-8 proven body, frozen). id = c + 8*(q*nTiles + n); group = q*8+c =
// b*TKS + t*KS + ks. Same-A blocks (all n, fixed group) share XCD c.
// LDS slot = row*4+pos, pos = kg ^ ((row>>1)&3).
template <int BN>
__global__ __launch_bounds__(256) void gemm_split(
    const unsigned short* __restrict__ A,     // [2048][aStride] bf16 (zero-padded)
    const unsigned short* __restrict__ WbT,   // [T][Npad][Kpad] bf16 (zero-padded)
    float* __restrict__ partial,              // [KS][2048][TNpad]
    int aStride, int tStride, int Kpad, int Npad, int KS, int TNpad,
    int nTiles, int TKS)
{
    const int tid = threadIdx.x;
    const int lane = tid & 63, w = tid >> 6;
    const int l15 = lane & 15, quad = lane >> 4;

    // swizzled decode
    const int id = blockIdx.x;
    const int c = id & 7;
    const int tmp = id >> 3;
    const int n = tmp % nTiles;
    const int q = tmp / nTiles;
    const int group = q * 8 + c;
    const int b0 = (group / TKS) * 128;
    const int rem = group % TKS;
    const int t = rem / KS;
    const int ksIdx = rem - t * KS;
    const int n0 = n * BN;

    __shared__ __align__(16) unsigned short As[2][128 * 32];   // 2 x 8 KB
    __shared__ __align__(16) unsigned short Bs[2][BN * 32];    // 2 x 8/4 KB

    const int S = Kpad >> 5;
    const int qb = S / KS, rb = S % KS;
    const int beg = ksIdx * qb + (ksIdx < rb ? ksIdx : rb);
    const int cnt = qb + (ksIdx < rb ? 1 : 0);

    constexpr int NF = BN / 32;
    const int wm = (w & 1) * 64;
    const int wn = (w >> 1) * (BN / 2);

    float4v acc[4][NF];
    #pragma unroll
    for (int a = 0; a < 4; a++)
        #pragma unroll
        for (int b = 0; b < NF; b++)
            acc[a][b] = (float4v){0.f, 0.f, 0.f, 0.f};

    // A staging: 512 granule-slots, 2 calls/wave
    const unsigned short* aSrc[2];
    int aOff[2];
    #pragma unroll
    for (int j = 0; j < 2; j++) {
        int s = (w * 2 + j) * 64 + lane;
        int r = s >> 2, kg = (s & 3) ^ ((r >> 1) & 3);
        aSrc[j] = A + (size_t)(b0 + r) * aStride + (size_t)t * tStride + kg * 8;
        aOff[j] = (w * 2 + j) * 512;           // shorts
    }
    // B staging
    constexpr int BCALLS = (BN == 128) ? 2 : 1;
    const unsigned short* bSrc[BCALLS];
    int bOff[BCALLS];
    #pragma unroll
    for (int j = 0; j < BCALLS; j++) {
        int s = (w * BCALLS + j) * 64 + lane;
        int r = s >> 2, kg = (s & 3) ^ ((r >> 1) & 3);
        bSrc[j] = WbT + ((size_t)t * Npad + n0 + r) * Kpad + kg * 8;
        bOff[j] = (w * BCALLS + j) * 512;
    }

    // prologue: stage step 0 into buf 0
    {
        const int k0 = beg << 5;
        #pragma unroll
        for (int j = 0; j < 2; j++)      stage16(aSrc[j] + k0, &As[0][aOff[j]], lane);
        #pragma unroll
        for (int j = 0; j < BCALLS; j++) stage16(bSrc[j] + k0, &Bs[0][bOff[j]], lane);
    }

    for (int s = 0; s < cnt; s++) {
        const int cur = s & 1;
        __syncthreads();   // drains cur-buf loads (in flight since prev iter) + prev compute
        if (s + 1 < cnt) {
            const int k1 = (beg + s + 1) << 5;
            #pragma unroll
            for (int j = 0; j < 2; j++)      stage16(aSrc[j] + k1, &As[cur ^ 1][aOff[j]], lane);
            #pragma unroll
            for (int j = 0; j < BCALLS; j++) stage16(bSrc[j] + k1, &Bs[cur ^ 1][bOff[j]], lane);
        }
        short8 af[4];
        #pragma unroll
        for (int fm = 0; fm < 4; fm++) {
            int m = wm + fm * 16 + l15;
            int pos = quad ^ ((m >> 1) & 3);
            af[fm] = *(const short8*)&As[cur][(m * 4 + pos) * 8];
        }
        short8 bfr[NF];
        #pragma unroll
        for (int fn = 0; fn < NF; fn++) {
            int nn = wn + fn * 16 + l15;
            int pos = quad ^ ((nn >> 1) & 3);
            bfr[fn] = *(const short8*)&Bs[cur][(nn * 4 + pos) * 8];
        }
        #pragma unroll
        for (int fm = 0; fm < 4; fm++)
            #pragma unroll
            for (int fn = 0; fn < NF; fn++)
                acc[fm][fn] = __builtin_amdgcn_mfma_f32_16x16x32_bf16(af[fm], bfr[fn], acc[fm][fn], 0, 0, 0);
    }

    const size_t pBase = ((size_t)ksIdx * BDIM + b0) * TNpad + (size_t)t * Npad + n0;
    #pragma unroll
    for (int fm = 0; fm < 4; fm++)
        #pragma unroll
        for (int r = 0; r < 4; r++) {
            const int m = wm + fm * 16 + quad * 4 + r;
            float* prow = partial + pBase + (size_t)m * TNpad + wn;
            #pragma unroll
            for (int fn = 0; fn < NF; fn++)
                prow[fn * 16 + l15] = acc[fm][fn][r];
        }
}

// ---- fused split-K reduce + bias + bf16 h store + per-chunk stats partials ----
__global__ __launch_bounds__(256) void reduce_bias_stats(
    const float* __restrict__ partial, const float* __restrict__ bias,
    unsigned short* __restrict__ h, float* __restrict__ sp,
    int T, int O, int Npad, int KS, int hstride, int TO)
{
    __shared__ float redS[4][64], redS2[4][64];
    const int colL = threadIdx.x & 63;
    const int cr = threadIdx.x >> 6;
    const int col = blockIdx.x * 64 + colL;
    const int chunk = blockIdx.y;
    float s = 0.f, s2 = 0.f;
    if (col < TO) {
        int t = col / O, o = col - t * O;
        const size_t TNpad = (size_t)T * Npad;
        const size_t pcol = (size_t)t * Npad + o;
        const float bv = bias[col];
        const int row0 = chunk * 128 + cr * 32;
        for (int r = 0; r < 32; r++) {
            const int row = row0 + r;
            const float* p = partial + (size_t)row * TNpad + pcol;
            float v = bv;
            for (int ks = 0; ks < KS; ks++) v += p[(size_t)ks * BDIM * TNpad];
            h[(size_t)row * hstride + col] = f2bf(v);
            s += v; s2 += v * v;
        }
    }
    redS[cr][colL] = s; redS2[cr][colL] = s2;
    __syncthreads();
    if (cr == 0 && col < TO) {
        float ts  = redS[0][colL] + redS[1][colL] + redS[2][colL] + redS[3][colL];
        float ts2 = redS2[0][colL] + redS2[1][colL] + redS2[2][colL] + redS2[3][colL];
        sp[(size_t)chunk * 2 * TO + col] = ts;
        sp[(size_t)chunk * 2 * TO + TO + col] = ts2;
    }
}

// ---- fold NC chunk partials -> per-col scale/shift ----
__global__ __launch_bounds__(256) void bn_scaleN(const float* __restrict__ sp,
                                                 const float* __restrict__ g,
                                                 const float* __restrict__ bb,
                                                 float* __restrict__ ss, int TO, int NC) {
    int col = blockIdx.x * 256 + threadIdx.x;
    if (col >= TO) return;
    float s = 0.f, s2 = 0.f;
    for (int c = 0; c < NC; c++) {
        s  += sp[(size_t)c * 2 * TO + col];
        s2 += sp[(size_t)c * 2 * TO + TO + col];
    }
    float mu = s * (1.f / BDIM);
    float var = s2 * (1.f / BDIM) - mu * mu;  // biased, matches jnp.var
    float scale = rsqrtf(var + 1e-5f) * g[col];
    ss[col] = scale;
    ss[TO + col] = bb[col] - mu * scale;
}

// ---- vectorized BN+tanh+head for O=20 in-place stages (s3) ----
template <int GPT>
__global__ __launch_bounds__(256) void bn_tanh_head_vec(
    unsigned short* hact, const float* __restrict__ ss,
    const float* __restrict__ hw, const float* __restrict__ hb,
    float* __restrict__ out,
    int T, int rowGran, int RPB, int hstride, int head_off)
{
    __shared__ float headAcc[256];
    const int tid = threadIdx.x;
    headAcc[tid] = 0.f;
    __syncthreads();
    const int b0 = blockIdx.x * RPB;

    uint2 hv[GPT];
    #pragma unroll
    for (int j = 0; j < GPT; j++) {
        int G = tid + j * 256;
        int r = G / rowGran, gg = G % rowGran;
        hv[j] = *(const uint2*)(hact + (size_t)(b0 + r) * hstride + gg * 4);
    }
    #pragma unroll
    for (int j = 0; j < GPT; j++) {
        int G = tid + j * 256;
        int r = G / rowGran, gg = G % rowGran;
        int c = gg * 4;
        float4 sc = *(const float4*)(ss + c);
        float4 sh = *(const float4*)(ss + hstride + c);
        float4 w4 = *(const float4*)(hw + c);
        union { unsigned short u[4]; uint2 v; } iv, ov;
        iv.v = hv[j];
        float a0 = fast_tanh(bf2f(iv.u[0]) * sc.x + sh.x);
        float a1 = fast_tanh(bf2f(iv.u[1]) * sc.y + sh.y);
        float a2 = fast_tanh(bf2f(iv.u[2]) * sc.z + sh.z);
        float a3 = fast_tanh(bf2f(iv.u[3]) * sc.w + sh.w);
        ov.u[0] = f2bf(a0); ov.u[1] = f2bf(a1); ov.u[2] = f2bf(a2); ov.u[3] = f2bf(a3);
        *(uint2*)(hact + (size_t)(b0 + r) * hstride + c) = ov.v;
        float partial = a0 * w4.x + a1 * w4.y + a2 * w4.z + a3 * w4.w;
        int t = gg / 5;
        atomicAdd(&headAcc[r * T + t], partial);
    }
    __syncthreads();
    if (tid < RPB * T) {
        int r = tid / T, t = tid % T;
        out[(size_t)(b0 + r) * OUTW + head_off + t] = headAcc[tid] + hb[t];
    }
}

// ---- BN + tanh + strided act store + head — WAVE variant ----
__global__ __launch_bounds__(256) void bn_tanh_head(
    const unsigned short* __restrict__ h, const float* __restrict__ ss,
    const float* __restrict__ hw, const float* __restrict__ hb,
    unsigned short* __restrict__ actOut, float* __restrict__ out,
    int T, int O, int hstride, int aRow, int GT, int GS, int head_off, int TO)
{
    int wid  = (blockIdx.x * 256 + threadIdx.x) >> 6;
    int lane = threadIdx.x & 63;
    int b = wid / T;
    int t = wid % T;
    const size_t hbase = (size_t)b * hstride + (size_t)t * O;
    const size_t abase = (size_t)b * aRow + (size_t)(t / GT) * GS + (size_t)(t % GT) * O;
    float hsum = 0.f;
    for (int o = lane; o < O; o += 64) {
        int col = t * O + o;
        float a = fast_tanh(bf2f(h[hbase + o]) * ss[col] + ss[TO + col]);
        if (actOut) actOut[abase + o] = f2bf(a);
        hsum += a * hw[col];
    }
    #pragma unroll
    for (int off = 32; off > 0; off >>= 1) hsum += __shfl_down(hsum, off, 64);
    if (lane == 0) out[(size_t)b * OUTW + head_off + t] = hsum + hb[t];
}

extern "C" void kernel_launch(void* const* d_in, const int* in_sizes, int n_in,
                              void* d_out, int out_size, void* d_ws, size_t ws_size,
                              hipStream_t stream)
{
    const float* x = (const float*)d_in[0];
    float* out = (float*)d_out;
    char* ws = (char*)d_ws;

    // ws layout (bytes)
    unsigned short* wbt  = (unsigned short*)(ws);              // 13,762,560
    unsigned short* ain0 = (unsigned short*)(ws + 13762560);   // 22,020,096 (2048x5376)
    unsigned short* bufA = (unsigned short*)(ws + 35782656);   // 20,971,520
    unsigned short* bufB = (unsigned short*)(ws + 56754176);   //  5,242,880
    unsigned short* ain1 = (unsigned short*)(ws + 61997056);   // 22,020,096
    unsigned short* bufC = (unsigned short*)(ws + 84017152);   //  5,046,272
    float*          ss   = (float*)(ws + 89063424);            //     40,960
    float*          sp0  = (float*)(ws + 89104384);            //    157,312 (16x2x1229)
    // overlays (all verified dead at use time):
    float* partial = (float*)(ws + 35782656);   // s1: 21 MB (=bufA), s0: 41.9 MB (bufA..ain1 head)
    float* sp4 = (float*)bufC;                  // 32x2x5120x4 = 1.31 MB (bufC free pre-s2)
    float* sp3 = (float*)bufC;                  // 0.33 MB
    float* sp2 = (float*)bufA;                  // 0.32 MB (act4 dead after s3 gemm)
    float* sp1 = (float*)bufB;                  // 0.32 MB (act3 dead after s2 gemm)
    unsigned short* xg = ain0 + 1232;           // full bf16 x copy, row stride 5376

    const float* W4 = (const float*)d_in[1];  const float* b4 = (const float*)d_in[2];
    const float* g4 = (const float*)d_in[3];  const float* bb4 = (const float*)d_in[4];
    const float* hw4 = (const float*)d_in[5]; const float* hb4 = (const float*)d_in[6];
    const float* W3 = (const float*)d_in[7];  const float* b3 = (const float*)d_in[8];
    const float* g3 = (const float*)d_in[9];  const float* bb3 = (const float*)d_in[10];
    const float* hw3 = (const float*)d_in[11]; const float* hb3 = (const float*)d_in[12];
    const float* W2 = (const float*)d_in[13]; const float* b2 = (const float*)d_in[14];
    const float* g2 = (const float*)d_in[15]; const float* bb2 = (const float*)d_in[16];
    const float* hw2 = (const float*)d_in[17]; const float* hb2 = (const float*)d_in[18];
    const float* W1 = (const float*)d_in[19]; const float* b1 = (const float*)d_in[20];
    const float* g1 = (const float*)d_in[21]; const float* bb1 = (const float*)d_in[22];
    const float* hw1 = (const float*)d_in[23]; const float* hb1 = (const float*)d_in[24];
    const float* W0 = (const float*)d_in[25]; const float* b0_ = (const float*)d_in[26];
    const float* g0 = (const float*)d_in[27]; const float* bb0 = (const float*)d_in[28];
    const float* hw0 = (const float*)d_in[29]; const float* hb0 = (const float*)d_in[30];

    // 1: fused x pack + weight conversions (s4..s1)
    pack_cvt<<<PACK_BLOCKS + 2896, 256, 0, stream>>>(x, ain0, ain1, W4, W3, W2, W1, wbt);

    // s4: T=256 I=16 O=20 — h never materialized.
    // pass1: in-register MFMA h -> column stats only
    s4_fused<false><<<1024, 256, 0, stream>>>(xg, wbt, b4, nullptr, nullptr, nullptr,
                                              nullptr, sp4, nullptr);
    bn_scaleN<<<20, 256, 0, stream>>>(sp4, g4, bb4, ss, 5120, 32);
    // pass2: recompute identical h -> BN+tanh -> act4 + head
    s4_fused<true><<<1024, 256, 0, stream>>>(xg, wbt, b4, ss, hw4, hb4,
                                             bufA, nullptr, out);

    // s3: T=64 I=144 O=20 Kpad=192, WbT @163840
    gemm_small<32, 64><<<dim3(1, 32, 64), 256, 0, stream>>>(bufA, xg, wbt + 163840, b3, bufB,
                                                            sp3, 64, 144, 20, 80, 64, 192, 1280, 1280);
    bn_scaleN<<<5, 256, 0, stream>>>(sp3, g3, bb3, ss, 1280, 32);
    bn_tanh_head_vec<5><<<BDIM / 4, 256, 0, stream>>>(bufB, ss, hw3, hb3, out, 64, 320, 4, 1280, 256);

    // s2: T=16 I=336 O=77 Kpad=384, WbT @409600
    gemm_small<64, 64><<<dim3(2, 32, 16), 256, 0, stream>>>(bufB, xg, wbt + 409600, b2, bufC,
                                                            sp2, 16, 336, 77, 80, 256, 384, 1232, 1232);
    bn_scaleN<<<5, 256, 0, stream>>>(sp2, g2, bb2, ss, 1232, 32);
    bn_tanh_head<<<BDIM * 16 / 4, 256, 0, stream>>>(bufC, ss, hw2, hb2,
                                                    ain1, out, 16, 77, 1232, 5376, 4, 1344, 320, 1232);

    // s1: T=4 I=1332 O=308 Kpad=1344 Npad=320 KS=2, WbT @882688
    // swizzled 1D grid: nTiles=5, TKS=T*KS=8, blocks = 5*16*8 = 640
    gemm_split<64><<<640, 256, 0, stream>>>(ain1, wbt + 882688, partial,
                                            5376, 1344, 1344, 320, 2, 1280, 5, 8);
    cvt_w<<<dim3(168, 40, 1), 256, 0, stream>>>(W0, wbt, 5328, 1229, 1280, 5376);  // overlaps s1 tail
    reduce_bias_stats<<<dim3(20, 16), 256, 0, stream>>>(partial, b1, bufC, sp1,
                                                        4, 308, 320, 2, 1232, 1232);
    bn_scaleN<<<5, 256, 0, stream>>>(sp1, g1, bb1, ss, 1232, 16);
    bn_tanh_head<<<BDIM * 4 / 4, 256, 0, stream>>>(bufC, ss, hw1, hb1,
                                                   ain0, out, 4, 308, 1232, 5376, 4, 0, 336, 1232);

    // s0: T=1 I=5328 O=1229 Kpad=5376 Npad=1280 KS=4
    // swizzled 1D grid: nTiles=10, TKS=4, blocks = 10*16*4 = 640
    gemm_split<128><<<640, 256, 0, stream>>>(ain0, wbt, partial,
                                             5376, 0, 5376, 1280, 4, 1280, 10, 4);
    reduce_bias_stats<<<dim3(20, 16), 256, 0, stream>>>(partial, b0_, bufC, sp0,
                                                        1, 1229, 1280, 4, 1232, 1229);
    bn_scaleN<<<5, 256, 0, stream>>>(sp0, g0, bb0, ss, 1229, 16);
    bn_tanh_head<<<BDIM / 4, 256, 0, stream>>>(bufC, ss, hw0, hb0,
                                               nullptr, out, 1, 1229, 1232, 1232, 1, 0, 340, 1229);
}